// Round 2
// baseline (82843.378 us; speedup 1.0000x reference)
//
#include <hip/hip_runtime.h>

// Seq2seq LSTM + attention — persistent-kernel version.
// Grid-wide sync: 256 blocks (1/CU, guaranteed co-resident) + atomic barrier.
// Layout: all activations feature-major, batch-minor [dim][64]: wave = 64 batches.
//
// Workspace: [64 floats: barrier counters][float arrays as below]

namespace {

__device__ __forceinline__ float fsigmoid(float x) {
    return 1.0f / (1.0f + __expf(-x));
}
__device__ __forceinline__ float ftanh(float x) {
    float e = __expf(2.0f * x);
    return 1.0f - 2.0f / (e + 1.0f);
}

// ---- grid barrier (all 256 blocks co-resident) ---------------------------
__device__ __forceinline__ void gridbar(unsigned* cnt, unsigned& epoch) {
    __threadfence();                 // release: flush this thread's stores device-wide
    __syncthreads();
    epoch += 256;
    if (threadIdx.x == 0) {
        __hip_atomic_fetch_add(cnt, 1u, __ATOMIC_RELEASE, __HIP_MEMORY_SCOPE_AGENT);
        while (__hip_atomic_load(cnt, __ATOMIC_ACQUIRE, __HIP_MEMORY_SCOPE_AGENT) < epoch)
            __builtin_amdgcn_s_sleep(1);
    }
    __syncthreads();
    __threadfence();                 // acquire: invalidate stale caches
}

// ---- transpose input_seq (B,S,F) -> xT[s][f][b] -------------------------
__global__ __launch_bounds__(256) void k_transpose_input(
    const float* __restrict__ in, float* __restrict__ xT)
{
    __shared__ float tile[64][65];
    int s  = blockIdx.x >> 2;
    int f0 = (blockIdx.x & 3) * 64;
    int lane = threadIdx.x & 63;
    int r0   = threadIdx.x >> 6;
    for (int r = r0; r < 64; r += 4)
        tile[r][lane] = in[(size_t)r * (512 * 256) + s * 256 + f0 + lane];
    __syncthreads();
    for (int r = r0; r < 64; r += 4)
        xT[((size_t)s * 256 + f0 + r) * 64 + lane] = tile[lane][r];
}

// ---- small weight/state transposes --------------------------------------
__global__ __launch_bounds__(256) void k_prep(
    const float* __restrict__ We_p, const float* __restrict__ Wh_p,
    const float* __restrict__ h0,   const float* __restrict__ c0,
    const float* __restrict__ Wa,
    float* __restrict__ We_pT, float* __restrict__ Wh_pT,
    float* __restrict__ encH0, float* __restrict__ cT,
    float* __restrict__ WahT,  float* __restrict__ WaeT)
{
    int idx = blockIdx.x * blockDim.x + threadIdx.x;
    const int total = 32768 * 4 + 4096 * 2;
    for (; idx < total; idx += gridDim.x * blockDim.x) {
        if (idx < 32768) {
            int u = idx >> 6, h = idx & 63;
            We_pT[idx] = We_p[h * 512 + u];
        } else if (idx < 65536) {
            int i2 = idx - 32768; int k = i2 >> 6, i = i2 & 63;
            Wh_pT[i2] = Wh_p[i * 512 + k];
        } else if (idx < 98304) {
            int i2 = idx - 65536; int u = i2 >> 6, b = i2 & 63;
            encH0[i2] = h0[b * 512 + u];
        } else if (idx < 131072) {
            int i2 = idx - 98304; int u = i2 >> 6, b = i2 & 63;
            cT[i2] = c0[b * 512 + u];
        } else if (idx < 135168) {
            int i2 = idx - 131072; int j = i2 >> 6, i = i2 & 63;
            WahT[i2] = Wa[i * 128 + j];
        } else {
            int i2 = idx - 135168; int h2 = i2 >> 6, h = i2 & 63;
            WaeT[i2] = Wa[h * 128 + 64 + h2];
        }
    }
}

// ---- one LSTM step core; c and biases in registers (valid for tid<128) ---
// block = 512 thr (8 waves), 2 hidden units / block, K=768 split 8 ways.
// float4 weight loads (wave-uniform), scalar activation loads (coalesced).
__device__ __forceinline__ void lstm_core(
    int u0, int tid,
    const float* __restrict__ x,     // [256][64]
    const float* __restrict__ hprev, // [512][64]
    float* __restrict__ hout,        // [512][64]
    float& creg, float b_i, float b_f, float b_g, float b_o,
    const float* __restrict__ Wih,   // [2048][256]
    const float* __restrict__ Whh,   // [2048][512]
    float* smem)                     // 4608 floats
{
    int lane = tid & 63;
    int w    = tid >> 6;
    float acc[2][4] = {{0.f,0.f,0.f,0.f},{0.f,0.f,0.f,0.f}};
    const float4* Wih4 = (const float4*)Wih;   // rows of 64 float4
    const float4* Whh4 = (const float4*)Whh;   // rows of 128 float4
    int ks = w * 96, ke = ks + 96;
    int xe = ke < 256 ? ke : 256;
    for (int k = ks; k < xe; k += 4) {
        float a0 = x[(k+0) * 64 + lane];
        float a1 = x[(k+1) * 64 + lane];
        float a2 = x[(k+2) * 64 + lane];
        float a3 = x[(k+3) * 64 + lane];
        #pragma unroll
        for (int uu = 0; uu < 2; ++uu)
            #pragma unroll
            for (int g = 0; g < 4; ++g) {
                float4 wv = Wih4[(size_t)(g * 512 + u0 + uu) * 64 + (k >> 2)];
                acc[uu][g] = fmaf(a0, wv.x, acc[uu][g]);
                acc[uu][g] = fmaf(a1, wv.y, acc[uu][g]);
                acc[uu][g] = fmaf(a2, wv.z, acc[uu][g]);
                acc[uu][g] = fmaf(a3, wv.w, acc[uu][g]);
            }
    }
    int hs = ks > 256 ? ks : 256;
    for (int k = hs; k < ke; k += 4) {
        int kk = k - 256;
        float a0 = hprev[(kk+0) * 64 + lane];
        float a1 = hprev[(kk+1) * 64 + lane];
        float a2 = hprev[(kk+2) * 64 + lane];
        float a3 = hprev[(kk+3) * 64 + lane];
        #pragma unroll
        for (int uu = 0; uu < 2; ++uu)
            #pragma unroll
            for (int g = 0; g < 4; ++g) {
                float4 wv = Whh4[(size_t)(g * 512 + u0 + uu) * 128 + (kk >> 2)];
                acc[uu][g] = fmaf(a0, wv.x, acc[uu][g]);
                acc[uu][g] = fmaf(a1, wv.y, acc[uu][g]);
                acc[uu][g] = fmaf(a2, wv.z, acc[uu][g]);
                acc[uu][g] = fmaf(a3, wv.w, acc[uu][g]);
            }
    }
    float* part = smem;          // [8][2][4][64]
    float* gsum = smem + 4096;   // [2][4][64]
    #pragma unroll
    for (int uu = 0; uu < 2; ++uu)
        #pragma unroll
        for (int g = 0; g < 4; ++g)
            part[((w * 2 + uu) * 4 + g) * 64 + lane] = acc[uu][g];
    __syncthreads();
    {
        int b = tid & 63, g = (tid >> 6) & 3, uu = tid >> 8;
        float s = 0.f;
        #pragma unroll
        for (int ww = 0; ww < 8; ++ww)
            s += part[((ww * 2 + uu) * 4 + g) * 64 + b];
        gsum[(uu * 4 + g) * 64 + b] = s;
    }
    __syncthreads();
    if (tid < 128) {
        int b = tid & 63, uu = tid >> 6;
        int u = u0 + uu;
        float gi = gsum[(uu * 4 + 0) * 64 + b] + b_i;
        float gf = gsum[(uu * 4 + 1) * 64 + b] + b_f;
        float gg = gsum[(uu * 4 + 2) * 64 + b] + b_g;
        float go = gsum[(uu * 4 + 3) * 64 + b] + b_o;
        float si = fsigmoid(gi), sf = fsigmoid(gf), so = fsigmoid(go);
        float tg = ftanh(gg);
        float cn = sf * creg + si * tg;
        creg = cn;
        hout[u * 64 + b] = so * ftanh(cn);
    }
}

// ---- persistent encoder: 512 steps, 1 grid barrier each ------------------
__global__ __launch_bounds__(512) void k_enc_persistent(
    const float* __restrict__ xT, float* __restrict__ encH,
    float* __restrict__ cT,
    const float* __restrict__ Wih, const float* __restrict__ Whh,
    const float* __restrict__ bias, unsigned* barcnt)
{
    __shared__ float smem[4608];
    int tid = threadIdx.x;
    int u0  = blockIdx.x * 2;
    float creg = 0.f, b_i = 0.f, b_f = 0.f, b_g = 0.f, b_o = 0.f;
    if (tid < 128) {
        int b = tid & 63, uu = tid >> 6; int u = u0 + uu;
        creg = cT[u * 64 + b];
        b_i = bias[u]; b_f = bias[512 + u]; b_g = bias[1024 + u]; b_o = bias[1536 + u];
    }
    unsigned epoch = 0;
    for (int t = 0; t < 512; ++t) {
        lstm_core(u0, tid, xT + (size_t)t * 16384,
                  encH + (size_t)t * 32768, encH + (size_t)(t + 1) * 32768,
                  creg, b_i, b_f, b_g, b_o, Wih, Whh, smem);
        gridbar(barcnt, epoch);
    }
    if (tid < 128) {
        int b = tid & 63, uu = tid >> 6; int u = u0 + uu;
        cT[u * 64 + b] = creg;   // hand cell state to decoder
    }
}

// ---- enc_proj + enc_attn (ba folded in), one parallel pass ---------------
__global__ __launch_bounds__(256) void k_proj_attn(
    const float* __restrict__ encH,  const float* __restrict__ We_pT,
    const float* __restrict__ be_p,  const float* __restrict__ WaeT,
    const float* __restrict__ ba,
    float* __restrict__ encProj, float* __restrict__ attnPre)
{
    int lane = threadIdx.x & 63;
    int w    = threadIdx.x >> 6;
    int wid  = blockIdx.x * 4 + w;
    int b    = wid >> 6;
    int soct = wid & 63;
    float acc[8];
    float bep = be_p[lane];
    #pragma unroll
    for (int j = 0; j < 8; ++j) acc[j] = bep;
    const float* hbase = encH + (size_t)(soct * 8 + 1) * 32768 + b;
    for (int u = 0; u < 512; ++u) {
        float wv = We_pT[u * 64 + lane];
        #pragma unroll
        for (int j = 0; j < 8; ++j)
            acc[j] = fmaf(hbase[(size_t)j * 32768 + u * 64], wv, acc[j]);
    }
    #pragma unroll
    for (int j = 0; j < 8; ++j)
        encProj[((size_t)b * 512 + soct * 8 + j) * 64 + lane] = acc[j];
    #pragma unroll
    for (int j = 0; j < 8; ++j) {
        float aa = ba[lane];
        for (int h2 = 0; h2 < 64; ++h2)
            aa = fmaf(__shfl(acc[j], h2), WaeT[h2 * 64 + lane], aa);
        attnPre[((size_t)b * 512 + soct * 8 + j) * 64 + lane] = aa;
    }
}

// ---- attention for one batch b (block of 512 threads) --------------------
__device__ __forceinline__ void attention_block(
    int b, int tid,
    const float* __restrict__ hcur,
    const float* __restrict__ Wh_pT, const float* __restrict__ bh_p,
    const float* __restrict__ WahT,  const float* __restrict__ v,
    const float* __restrict__ attnPre, const float* __restrict__ encProj,
    float* __restrict__ ctxT, float* smem)
{
    int lane = tid & 63, w = tid >> 6;
    float* hq     = smem;
    float* hWa    = smem + 64;
    float* scores = smem + 128;
    float* part   = smem + 640;
    float* red    = smem + 1152;
    {
        float p = 0.f;
        int k0 = w * 64;
        #pragma unroll 4
        for (int kk = 0; kk < 64; ++kk) {
            int k = k0 + kk;
            p = fmaf(hcur[k * 64 + b], Wh_pT[k * 64 + lane], p);
        }
        part[w * 64 + lane] = p;
    }
    __syncthreads();
    if (tid < 64) {
        float s = bh_p[tid];
        #pragma unroll
        for (int ww = 0; ww < 8; ++ww) s += part[ww * 64 + tid];
        hq[tid] = s;
    }
    __syncthreads();
    if (tid < 64) {
        float s = 0.f;
        for (int j = 0; j < 64; ++j)
            s = fmaf(hq[j], WahT[j * 64 + tid], s);
        hWa[tid] = s;
    }
    __syncthreads();
    {
        float hw = hWa[lane];
        float vv = v[lane];
        for (int s2 = w; s2 < 512; s2 += 8) {
            float e = ftanh(hw + attnPre[((size_t)b * 512 + s2) * 64 + lane]) * vv;
            #pragma unroll
            for (int off = 32; off > 0; off >>= 1)
                e += __shfl_down(e, off);
            if (lane == 0) scores[s2] = e;
        }
    }
    __syncthreads();
    float sc = scores[tid];
    float m = sc;
    #pragma unroll
    for (int off = 32; off > 0; off >>= 1)
        m = fmaxf(m, __shfl_xor(m, off));
    if (lane == 0) red[w] = m;
    __syncthreads();
    if (tid == 0) {
        float mm = red[0];
        for (int ww = 1; ww < 8; ++ww) mm = fmaxf(mm, red[ww]);
        red[8] = mm;
    }
    __syncthreads();
    float M = red[8];
    float ex = __expf(sc - M);
    scores[tid] = ex;
    float ssum = ex;
    #pragma unroll
    for (int off = 32; off > 0; off >>= 1)
        ssum += __shfl_xor(ssum, off);
    if (lane == 0) red[w] = ssum;
    __syncthreads();
    if (tid == 0) {
        float tt = 0.f;
        for (int ww = 0; ww < 8; ++ww) tt += red[ww];
        red[8] = 1.0f / tt;
    }
    __syncthreads();
    float inv = red[8];
    {
        float a = 0.f;
        for (int s2 = w; s2 < 512; s2 += 8)
            a = fmaf(scores[s2], encProj[((size_t)b * 512 + s2) * 64 + lane], a);
        part[w * 64 + lane] = a;
    }
    __syncthreads();
    if (tid < 64) {
        float s = 0.f;
        #pragma unroll
        for (int ww = 0; ww < 8; ++ww) s += part[ww * 64 + tid];
        ctxT[tid * 64 + b] = s * inv;
    }
}

// ---- decoder LSTM task with global c ------------------------------------
__device__ __forceinline__ void dec_lstm_task(
    int task, int tid,
    const float* __restrict__ x, const float* __restrict__ hcur,
    float* __restrict__ hnext, float* __restrict__ cT,
    const float* __restrict__ Wih, const float* __restrict__ Whh,
    const float* __restrict__ bias, float* smem)
{
    int u0 = task * 2;
    float creg = 0.f, b_i = 0.f, b_f = 0.f, b_g = 0.f, b_o = 0.f;
    if (tid < 128) {
        int b = tid & 63, uu = tid >> 6; int u = u0 + uu;
        creg = cT[u * 64 + b];
        b_i = bias[u]; b_f = bias[512 + u]; b_g = bias[1024 + u]; b_o = bias[1536 + u];
    }
    lstm_core(u0, tid, x, hcur, hnext, creg, b_i, b_f, b_g, b_o, Wih, Whh, smem);
    if (tid < 128) {
        int b = tid & 63, uu = tid >> 6; int u = u0 + uu;
        cT[u * 64 + b] = creg;
    }
}

// ---- output row: out[f] = dot([hnext, ctx], Wo[f]) + bo[f] ---------------
__device__ __forceinline__ void out_row(
    int f, int tid,
    const float* __restrict__ hn, const float* __restrict__ ctxT,
    const float* __restrict__ Wo, const float* __restrict__ bo,
    float* __restrict__ outT, float* __restrict__ dout, int t, float* smem)
{
    int lane = tid & 63, w = tid >> 6;
    const float4* W4 = (const float4*)(Wo + (size_t)f * 576);
    float acc = 0.f;
    int k0 = w * 72;
    for (int k = k0; k < k0 + 72; k += 4) {
        float4 wv = W4[k >> 2];
        float a0, a1, a2, a3;
        if (k < 512) {
            a0 = hn[(k+0) * 64 + lane]; a1 = hn[(k+1) * 64 + lane];
            a2 = hn[(k+2) * 64 + lane]; a3 = hn[(k+3) * 64 + lane];
        } else {
            int kk = k - 512;
            a0 = ctxT[(kk+0) * 64 + lane]; a1 = ctxT[(kk+1) * 64 + lane];
            a2 = ctxT[(kk+2) * 64 + lane]; a3 = ctxT[(kk+3) * 64 + lane];
        }
        acc = fmaf(a0, wv.x, acc); acc = fmaf(a1, wv.y, acc);
        acc = fmaf(a2, wv.z, acc); acc = fmaf(a3, wv.w, acc);
    }
    smem[w * 64 + lane] = acc;
    __syncthreads();
    if (tid < 64) {
        float s = bo[f];
        #pragma unroll
        for (int ww = 0; ww < 8; ++ww) s += smem[ww * 64 + tid];
        outT[f * 64 + tid] = s;
        if (f == 255) dout[tid * 96 + t] = s;
    }
}

// ---- persistent decoder: 96 steps × 2 phases -----------------------------
__global__ __launch_bounds__(512) void k_dec_persistent(
    const float* __restrict__ xLast, float* __restrict__ outT,
    const float* __restrict__ encHend,
    float* __restrict__ hbuf0, float* __restrict__ hbuf1,
    float* __restrict__ cT,
    const float* __restrict__ Wih, const float* __restrict__ Whh,
    const float* __restrict__ bias,
    const float* __restrict__ Wh_pT, const float* __restrict__ bh_p,
    const float* __restrict__ WahT,  const float* __restrict__ v,
    const float* __restrict__ attnPre, const float* __restrict__ encProj,
    float* __restrict__ ctxT,
    const float* __restrict__ Wo, const float* __restrict__ bo,
    float* __restrict__ dout, unsigned* barcnt)
{
    __shared__ float smem[4608];
    int tid = threadIdx.x;
    int bi  = blockIdx.x;
    unsigned epoch = 0;
    for (int t = 0; t < 96; ++t) {
        const float* x  = (t == 0) ? xLast : outT;
        const float* hc = (t == 0) ? encHend : ((t & 1) ? hbuf0 : hbuf1);
        float* hn = (t & 1) ? hbuf1 : hbuf0;
        // Phase 1: attention (blocks 0..63) || LSTM (tasks 0..255 on blocks 64..255)
        if (bi < 64) {
            attention_block(bi, tid, hc, Wh_pT, bh_p, WahT, v,
                            attnPre, encProj, ctxT, smem);
        } else {
            dec_lstm_task(bi - 64, tid, x, hc, hn, cT, Wih, Whh, bias, smem);
            if (bi < 128)
                dec_lstm_task(bi + 128, tid, x, hc, hn, cT, Wih, Whh, bias, smem);
        }
        gridbar(barcnt, epoch);
        // Phase 2: output projection, one f-row per block; writes feedback x
        out_row(bi, tid, hn, ctxT, Wo, bo, outT, dout, t, smem);
        gridbar(barcnt, epoch);
    }
}

} // namespace

extern "C" void kernel_launch(void* const* d_in, const int* in_sizes, int n_in,
                              void* d_out, int out_size, void* d_ws, size_t ws_size,
                              hipStream_t stream)
{
    (void)in_sizes; (void)n_in; (void)out_size; (void)ws_size;
    const float* input_seq = (const float*)d_in[0];
    const float* h0     = (const float*)d_in[1];
    const float* c0     = (const float*)d_in[2];
    const float* W_ih_e = (const float*)d_in[3];
    const float* W_hh_e = (const float*)d_in[4];
    const float* b_e    = (const float*)d_in[5];
    const float* W_ih_d = (const float*)d_in[6];
    const float* W_hh_d = (const float*)d_in[7];
    const float* b_d    = (const float*)d_in[8];
    const float* We_p   = (const float*)d_in[9];
    const float* be_p   = (const float*)d_in[10];
    const float* Wh_p   = (const float*)d_in[11];
    const float* bh_p   = (const float*)d_in[12];
    const float* Wa     = (const float*)d_in[13];
    const float* ba     = (const float*)d_in[14];
    const float* v      = (const float*)d_in[15];
    const float* Wo     = (const float*)d_in[16];
    const float* bo     = (const float*)d_in[17];
    float* out = (float*)d_out;

    unsigned* barcnt = (unsigned*)d_ws;          // [0]=enc, [16]=dec
    float* ws      = (float*)d_ws + 64;
    float* xT      = ws;                      // 8388608
    float* encH    = xT + 8388608;            // 513*32768 = 16809984
    float* cT      = encH + 16809984;         // 32768
    float* We_pT   = cT + 32768;              // 32768
    float* Wh_pT   = We_pT + 32768;           // 32768
    float* WahT    = Wh_pT + 32768;           // 4096
    float* WaeT    = WahT + 4096;             // 4096
    float* encProj = WaeT + 4096;             // 2097152
    float* attnPre = encProj + 2097152;       // 2097152
    float* hbuf0   = attnPre + 2097152;       // 32768
    float* hbuf1   = hbuf0 + 32768;           // 32768
    float* ctxT    = hbuf1 + 32768;           // 4096
    float* outT    = ctxT + 4096;             // 16384

    hipMemsetAsync(d_ws, 0, 256, stream);     // zero barrier counters
    k_transpose_input<<<2048, 256, 0, stream>>>(input_seq, xT);
    k_prep<<<544, 256, 0, stream>>>(We_p, Wh_p, h0, c0, Wa,
                                    We_pT, Wh_pT, encH, cT, WahT, WaeT);
    k_enc_persistent<<<256, 512, 0, stream>>>(xT, encH, cT, W_ih_e, W_hh_e, b_e,
                                              barcnt);
    k_proj_attn<<<1024, 256, 0, stream>>>(encH, We_pT, be_p, WaeT, ba,
                                          encProj, attnPre);
    k_dec_persistent<<<256, 512, 0, stream>>>(xT + (size_t)511 * 16384, outT,
                                              encH + (size_t)512 * 32768,
                                              hbuf0, hbuf1, cT,
                                              W_ih_d, W_hh_d, b_d,
                                              Wh_pT, bh_p, WahT, v,
                                              attnPre, encProj, ctxT,
                                              Wo, bo, out, barcnt + 16);
}

// Round 3
// 15959.348 us; speedup vs baseline: 5.1909x; 5.1909x over previous
//
#include <hip/hip_runtime.h>

// Seq2seq LSTM + attention — persistent kernels with FENCE-FREE grid barriers.
//
// Why: __threadfence() at agent scope on gfx950 = buffer_wbl2+buffer_inv (full
// per-XCD L2 writeback+invalidate) => 86us/barrier measured in round 2.
// Instead: every cross-block datum is written EXACTLY ONCE to a NEVER-REUSED
// address via a relaxed agent-scope atomic store (global_store ... sc1, coherent
// at memory-side L3, no cache maintenance). Readers use plain cached loads —
// safe because no XCD can hold a stale copy of a fresh address. The barrier is
// then just s_waitcnt vmcnt(0) + relaxed atomic counter.
//
// Layouts: activations feature-major batch-minor. x float4-packed on f,
// h float2-packed on u (writer thread owns both units of a pair).

namespace {

__device__ __forceinline__ float fsigmoid(float x) {
    return 1.0f / (1.0f + __expf(-x));
}
__device__ __forceinline__ float ftanh(float x) {
    float e = __expf(2.0f * x);
    return 1.0f - 2.0f / (e + 1.0f);
}

__device__ __forceinline__ void coh_store(float* p, float v) {
    __hip_atomic_store(p, v, __ATOMIC_RELAXED, __HIP_MEMORY_SCOPE_AGENT);
}
__device__ __forceinline__ void coh_store2(float* p, float2 v) {
    union { float2 f; unsigned long long u; } cv; cv.f = v;
    __hip_atomic_store((unsigned long long*)p, cv.u,
                       __ATOMIC_RELAXED, __HIP_MEMORY_SCOPE_AGENT);
}

// ---- fence-free grid barrier (256 co-resident blocks) --------------------
__device__ __forceinline__ void gridbar(unsigned* cnt, unsigned& epoch) {
    asm volatile("s_waitcnt vmcnt(0)" ::: "memory");  // drain sc1 data stores
    __syncthreads();
    epoch += 256;
    if (threadIdx.x == 0) {
        __hip_atomic_fetch_add(cnt, 1u, __ATOMIC_RELAXED, __HIP_MEMORY_SCOPE_AGENT);
        while (__hip_atomic_load(cnt, __ATOMIC_RELAXED, __HIP_MEMORY_SCOPE_AGENT) < epoch)
            __builtin_amdgcn_s_sleep(2);
    }
    __syncthreads();
    asm volatile("" ::: "memory");
}

// ---- transpose input_seq (B,S,F) -> xT4[s][f/4][b] (float4 on f) ---------
__global__ __launch_bounds__(256) void k_transpose_input(
    const float* __restrict__ in, float4* __restrict__ xT4)
{
    __shared__ float tile[64][65];
    int s  = blockIdx.x >> 2;
    int f0 = (blockIdx.x & 3) * 64;
    int lane = threadIdx.x & 63;
    int r0   = threadIdx.x >> 6;
    for (int r = r0; r < 64; r += 4)
        tile[r][lane] = in[(size_t)r * (512 * 256) + s * 256 + f0 + lane];
    __syncthreads();
    for (int q = r0; q < 16; q += 4) {
        float4 vv = make_float4(tile[lane][4*q], tile[lane][4*q+1],
                                tile[lane][4*q+2], tile[lane][4*q+3]);
        xT4[((size_t)s * 64 + (f0 >> 2) + q) * 64 + lane] = vv;
    }
}

// ---- small weight/state transposes --------------------------------------
// encH slot0 is float2-packed on u: encH0[(u>>1)*128 + b*2 + (u&1)]
__global__ __launch_bounds__(256) void k_prep(
    const float* __restrict__ We_p, const float* __restrict__ Wh_p,
    const float* __restrict__ h0,   const float* __restrict__ c0,
    const float* __restrict__ Wa,
    float* __restrict__ We_pT, float* __restrict__ Wh_pT,
    float* __restrict__ encH0, float* __restrict__ cT,
    float* __restrict__ WahT,  float* __restrict__ WaeT)
{
    int idx = blockIdx.x * blockDim.x + threadIdx.x;
    const int total = 32768 * 4 + 4096 * 2;
    for (; idx < total; idx += gridDim.x * blockDim.x) {
        if (idx < 32768) {
            int u = idx >> 6, h = idx & 63;
            We_pT[idx] = We_p[h * 512 + u];
        } else if (idx < 65536) {
            int i2 = idx - 32768; int k = i2 >> 6, i = i2 & 63;
            Wh_pT[i2] = Wh_p[i * 512 + k];
        } else if (idx < 98304) {
            int i2 = idx - 65536; int u = i2 >> 6, b = i2 & 63;
            encH0[(u >> 1) * 128 + b * 2 + (u & 1)] = h0[b * 512 + u];
        } else if (idx < 131072) {
            int i2 = idx - 98304; int u = i2 >> 6, b = i2 & 63;
            cT[i2] = c0[b * 512 + u];
        } else if (idx < 135168) {
            int i2 = idx - 131072; int j = i2 >> 6, i = i2 & 63;
            WahT[i2] = Wa[i * 128 + j];
        } else {
            int i2 = idx - 135168; int h2 = i2 >> 6, h = i2 & 63;
            WaeT[i2] = Wa[h * 128 + 64 + h2];
        }
    }
}

// ---- one LSTM step; block = 512 thr, 2 hidden units, K split 8 ways ------
// Weights: wave-uniform indices (readfirstlane) -> s_load_dwordx4.
// x: float4-packed (XP) or scalar rows [f][b]. hprev/hout: float2-packed on u.
template<bool XP>
__device__ __forceinline__ void lstm_core(
    int u0, int tid,
    const float4* __restrict__ x4, const float* __restrict__ xs,
    const float* __restrict__ hprev, float* __restrict__ hout,
    float2& creg, const float* __restrict__ bias,
    const float4* __restrict__ Wih4, const float4* __restrict__ Whh4,
    float* smem)
{
    int lane = tid & 63;
    int w    = __builtin_amdgcn_readfirstlane(tid >> 6);
    float acc[8];
    #pragma unroll
    for (int r = 0; r < 8; ++r) acc[r] = 0.f;
    const int ks = w * 96, ke = ks + 96;
    const int xe = ke < 256 ? ke : 256;
    if constexpr (XP) {
        for (int q = ks >> 2; q < (xe >> 2); ++q) {
            float4 a = x4[q * 64 + lane];
            #pragma unroll
            for (int uu = 0; uu < 2; ++uu)
                #pragma unroll
                for (int g = 0; g < 4; ++g) {
                    float4 wv = Wih4[(size_t)(g * 512 + u0 + uu) * 64 + q];
                    float& A = acc[uu * 4 + g];
                    A = fmaf(a.x, wv.x, A); A = fmaf(a.y, wv.y, A);
                    A = fmaf(a.z, wv.z, A); A = fmaf(a.w, wv.w, A);
                }
        }
    } else {
        for (int k = ks; k < xe; k += 4) {
            float a0 = xs[(k+0)*64 + lane], a1 = xs[(k+1)*64 + lane];
            float a2 = xs[(k+2)*64 + lane], a3 = xs[(k+3)*64 + lane];
            #pragma unroll
            for (int uu = 0; uu < 2; ++uu)
                #pragma unroll
                for (int g = 0; g < 4; ++g) {
                    float4 wv = Wih4[(size_t)(g * 512 + u0 + uu) * 64 + (k >> 2)];
                    float& A = acc[uu * 4 + g];
                    A = fmaf(a0, wv.x, A); A = fmaf(a1, wv.y, A);
                    A = fmaf(a2, wv.z, A); A = fmaf(a3, wv.w, A);
                }
        }
    }
    const float2* h2 = (const float2*)hprev;
    int hs = ks > 256 ? ks : 256;
    for (int k = hs; k < ke; k += 4) {
        int kk = k - 256;
        float2 p0 = h2[(kk >> 1)       * 64 + lane];
        float2 p1 = h2[((kk >> 1) + 1) * 64 + lane];
        #pragma unroll
        for (int uu = 0; uu < 2; ++uu)
            #pragma unroll
            for (int g = 0; g < 4; ++g) {
                float4 wv = Whh4[(size_t)(g * 512 + u0 + uu) * 128 + (kk >> 2)];
                float& A = acc[uu * 4 + g];
                A = fmaf(p0.x, wv.x, A); A = fmaf(p0.y, wv.y, A);
                A = fmaf(p1.x, wv.z, A); A = fmaf(p1.y, wv.w, A);
            }
    }
    float* part = smem;          // [8][8][64]
    float* gsum = smem + 4096;   // [8][64]
    #pragma unroll
    for (int r = 0; r < 8; ++r)
        part[(w * 8 + r) * 64 + lane] = acc[r];
    __syncthreads();
    {
        int b = tid & 63, r = tid >> 6;
        float s = 0.f;
        #pragma unroll
        for (int ww = 0; ww < 8; ++ww)
            s += part[(ww * 8 + r) * 64 + b];
        gsum[r * 64 + b] = s;
    }
    __syncthreads();
    if (tid < 64) {
        int b = tid;
        float cc[2] = {creg.x, creg.y};
        float hv[2];
        #pragma unroll
        for (int uu = 0; uu < 2; ++uu) {
            int u = u0 + uu;
            float gi = gsum[(uu*4+0)*64 + b] + bias[u];
            float gf = gsum[(uu*4+1)*64 + b] + bias[512 + u];
            float gg = gsum[(uu*4+2)*64 + b] + bias[1024 + u];
            float go = gsum[(uu*4+3)*64 + b] + bias[1536 + u];
            float si = fsigmoid(gi), sf = fsigmoid(gf), so = fsigmoid(go);
            float tg = ftanh(gg);
            float cn = sf * cc[uu] + si * tg;
            cc[uu] = cn;
            hv[uu] = so * ftanh(cn);
        }
        creg = make_float2(cc[0], cc[1]);
        coh_store2(hout + (u0 >> 1) * 128 + b * 2, make_float2(hv[0], hv[1]));
    }
}

// ---- persistent encoder: 512 steps, 1 fence-free barrier each ------------
__global__ __launch_bounds__(512) void k_enc_persistent(
    const float4* __restrict__ xT4, float* __restrict__ encH,
    float* __restrict__ cT,
    const float* __restrict__ Wih, const float* __restrict__ Whh,
    const float* __restrict__ bias, unsigned* barcnt)
{
    __shared__ float smem[4608];
    int tid = threadIdx.x;
    int u0  = blockIdx.x * 2;
    float2 creg = make_float2(0.f, 0.f);
    if (tid < 64) {
        creg.x = cT[u0 * 64 + tid];
        creg.y = cT[(u0 + 1) * 64 + tid];
    }
    const float4* Wih4 = (const float4*)Wih;
    const float4* Whh4 = (const float4*)Whh;
    unsigned epoch = 0;
    for (int t = 0; t < 512; ++t) {
        lstm_core<true>(u0, tid, xT4 + (size_t)t * 4096, nullptr,
                        encH + (size_t)t * 32768, encH + (size_t)(t + 1) * 32768,
                        creg, bias, Wih4, Whh4, smem);
        gridbar(barcnt, epoch);
    }
    if (tid < 64) {
        cT[u0 * 64 + tid] = creg.x;
        cT[(u0 + 1) * 64 + tid] = creg.y;
    }
}

// ---- enc_proj + enc_attn (ba folded), parallel pass ----------------------
__global__ __launch_bounds__(256) void k_proj_attn(
    const float* __restrict__ encH,  const float* __restrict__ We_pT,
    const float* __restrict__ be_p,  const float* __restrict__ WaeT,
    const float* __restrict__ ba,
    float* __restrict__ encProj, float* __restrict__ attnPre)
{
    int lane = threadIdx.x & 63;
    int w    = __builtin_amdgcn_readfirstlane((int)threadIdx.x >> 6);
    int wid  = blockIdx.x * 4 + w;
    int b    = wid >> 6;
    int soct = wid & 63;
    float acc[8];
    float bep = be_p[lane];
    #pragma unroll
    for (int j = 0; j < 8; ++j) acc[j] = bep;
    for (int p = 0; p < 256; ++p) {
        float wv0 = We_pT[(2*p)   * 64 + lane];
        float wv1 = We_pT[(2*p+1) * 64 + lane];
        #pragma unroll
        for (int j = 0; j < 8; ++j) {
            const float2* hb2 = (const float2*)(encH + (size_t)(soct*8 + j + 1) * 32768);
            float2 hv = hb2[p * 64 + b];
            acc[j] = fmaf(hv.x, wv0, acc[j]);
            acc[j] = fmaf(hv.y, wv1, acc[j]);
        }
    }
    #pragma unroll
    for (int j = 0; j < 8; ++j)
        encProj[((size_t)b * 512 + soct * 8 + j) * 64 + lane] = acc[j];
    #pragma unroll
    for (int j = 0; j < 8; ++j) {
        float aa = ba[lane];
        for (int h2 = 0; h2 < 64; ++h2)
            aa = fmaf(__shfl(acc[j], h2), WaeT[h2 * 64 + lane], aa);
        attnPre[((size_t)b * 512 + soct * 8 + j) * 64 + lane] = aa;
    }
}

// ---- attention for one batch b (block of 512 threads) --------------------
__device__ __forceinline__ void attention_block(
    int b, int tid,
    const float* __restrict__ hcur,     // float2-packed
    const float* __restrict__ Wh_pT, const float* __restrict__ bh_p,
    const float* __restrict__ WahT,  const float* __restrict__ v,
    const float* __restrict__ attnPre, const float* __restrict__ encProj,
    float* __restrict__ ctx, float* smem)
{
    int lane = tid & 63;
    int w    = __builtin_amdgcn_readfirstlane(tid >> 6);
    float* hq     = smem;
    float* hWa    = smem + 64;
    float* scores = smem + 128;
    float* part   = smem + 640;
    float* red    = smem + 1152;
    {
        const float2* h2 = (const float2*)hcur;
        float p = 0.f;
        int k0 = w * 64;
        for (int kk = 0; kk < 64; kk += 2) {
            float2 hv = h2[((k0 + kk) >> 1) * 64 + b];
            p = fmaf(hv.x, Wh_pT[(k0 + kk)     * 64 + lane], p);
            p = fmaf(hv.y, Wh_pT[(k0 + kk + 1) * 64 + lane], p);
        }
        part[w * 64 + lane] = p;
    }
    __syncthreads();
    if (tid < 64) {
        float s = bh_p[tid];
        #pragma unroll
        for (int ww = 0; ww < 8; ++ww) s += part[ww * 64 + tid];
        hq[tid] = s;
    }
    __syncthreads();
    if (tid < 64) {
        float s = 0.f;
        for (int j = 0; j < 64; ++j)
            s = fmaf(hq[j], WahT[j * 64 + tid], s);
        hWa[tid] = s;
    }
    __syncthreads();
    {
        float hw = hWa[lane];
        float vv = v[lane];
        for (int s2 = w; s2 < 512; s2 += 8) {
            float e = ftanh(hw + attnPre[((size_t)b * 512 + s2) * 64 + lane]) * vv;
            #pragma unroll
            for (int off = 32; off > 0; off >>= 1)
                e += __shfl_down(e, off);
            if (lane == 0) scores[s2] = e;
        }
    }
    __syncthreads();
    float sc = scores[tid];
    float m = sc;
    #pragma unroll
    for (int off = 32; off > 0; off >>= 1)
        m = fmaxf(m, __shfl_xor(m, off));
    if (lane == 0) red[w] = m;
    __syncthreads();
    if (tid == 0) {
        float mm = red[0];
        for (int ww = 1; ww < 8; ++ww) mm = fmaxf(mm, red[ww]);
        red[8] = mm;
    }
    __syncthreads();
    float M = red[8];
    float ex = __expf(sc - M);
    scores[tid] = ex;
    float ssum = ex;
    #pragma unroll
    for (int off = 32; off > 0; off >>= 1)
        ssum += __shfl_xor(ssum, off);
    if (lane == 0) red[w] = ssum;
    __syncthreads();
    if (tid == 0) {
        float tt = 0.f;
        for (int ww = 0; ww < 8; ++ww) tt += red[ww];
        red[8] = 1.0f / tt;
    }
    __syncthreads();
    float inv = red[8];
    {
        float a = 0.f;
        for (int s2 = w; s2 < 512; s2 += 8)
            a = fmaf(scores[s2], encProj[((size_t)b * 512 + s2) * 64 + lane], a);
        part[w * 64 + lane] = a;
    }
    __syncthreads();
    if (tid < 64) {
        float s = 0.f;
        #pragma unroll
        for (int ww = 0; ww < 8; ++ww) s += part[ww * 64 + tid];
        coh_store(&ctx[tid * 64 + b], s * inv);
    }
}

// ---- output row f: out[f] = dot([h, ctx], Wo[f]) + bo[f] -----------------
__device__ __forceinline__ void out_row(
    int f, int tid, int t,
    const float* __restrict__ hn,   // float2-packed
    const float* __restrict__ ctx,  // [64][64]
    const float* __restrict__ Wo, const float* __restrict__ bo,
    float* __restrict__ outrow, float* __restrict__ dout, float* smem)
{
    int lane = tid & 63;
    int w    = __builtin_amdgcn_readfirstlane(tid >> 6);
    const float4* W4 = (const float4*)(Wo + (size_t)f * 576);
    const float2* h2 = (const float2*)hn;
    float acc = 0.f;
    int k0 = w * 72;
    for (int k = k0; k < k0 + 72; k += 4) {
        float4 wv = W4[k >> 2];
        float a0, a1, a2, a3;
        if (k < 512) {
            float2 p0 = h2[(k >> 1)       * 64 + lane];
            float2 p1 = h2[((k >> 1) + 1) * 64 + lane];
            a0 = p0.x; a1 = p0.y; a2 = p1.x; a3 = p1.y;
        } else {
            int kk = k - 512;
            a0 = ctx[(kk+0)*64 + lane]; a1 = ctx[(kk+1)*64 + lane];
            a2 = ctx[(kk+2)*64 + lane]; a3 = ctx[(kk+3)*64 + lane];
        }
        acc = fmaf(a0, wv.x, acc); acc = fmaf(a1, wv.y, acc);
        acc = fmaf(a2, wv.z, acc); acc = fmaf(a3, wv.w, acc);
    }
    smem[w * 64 + lane] = acc;
    __syncthreads();
    if (tid < 64) {
        float s = bo[f];
        #pragma unroll
        for (int ww = 0; ww < 8; ++ww) s += smem[ww * 64 + tid];
        coh_store(&outrow[f * 64 + tid], s);
        if (f == 255) dout[tid * 96 + t] = s;
    }
}

// ---- persistent decoder: 96 steps × (attn||LSTM, out) --------------------
__global__ __launch_bounds__(512) void k_dec_persistent(
    const float4* __restrict__ xT4last,
    const float* __restrict__ encHend,
    float* __restrict__ dechH,            // [96][256][64] float2-packed
    float* __restrict__ cT,
    const float* __restrict__ Wih, const float* __restrict__ Whh,
    const float* __restrict__ bias,
    const float* __restrict__ Wh_pT, const float* __restrict__ bh_p,
    const float* __restrict__ WahT,  const float* __restrict__ v,
    const float* __restrict__ attnPre, const float* __restrict__ encProj,
    float* __restrict__ ctxH,             // [96][64][64]
    const float* __restrict__ Wo, const float* __restrict__ bo,
    float* __restrict__ outH,             // [96][256][64]
    float* __restrict__ dout, unsigned* barcnt)
{
    __shared__ float smem[4608];
    int tid = threadIdx.x;
    int bi  = blockIdx.x;
    const float4* Wih4 = (const float4*)Wih;
    const float4* Whh4 = (const float4*)Whh;
    int taskA = -1, taskB = -1;
    if (bi >= 64) { taskA = bi - 64; if (bi < 128) taskB = bi + 128; }
    float2 cA = make_float2(0.f, 0.f), cB = cA;
    if (taskA >= 0 && tid < 64) {
        int u0 = taskA * 2;
        cA.x = cT[u0 * 64 + tid]; cA.y = cT[(u0 + 1) * 64 + tid];
    }
    if (taskB >= 0 && tid < 64) {
        int u0 = taskB * 2;
        cB.x = cT[u0 * 64 + tid]; cB.y = cT[(u0 + 1) * 64 + tid];
    }
    unsigned epoch = 0;
    for (int t = 0; t < 96; ++t) {
        const float* hc = (t == 0) ? encHend : dechH + (size_t)(t - 1) * 32768;
        float* hn = dechH + (size_t)t * 32768;
        if (bi < 64) {
            attention_block(bi, tid, hc, Wh_pT, bh_p, WahT, v,
                            attnPre, encProj, ctxH + (size_t)t * 4096, smem);
        } else {
            const float* xs = (t == 0) ? nullptr : outH + (size_t)(t - 1) * 16384;
            if (t == 0)
                lstm_core<true>(taskA * 2, tid, xT4last, nullptr, hc, hn, cA, bias, Wih4, Whh4, smem);
            else
                lstm_core<false>(taskA * 2, tid, nullptr, xs, hc, hn, cA, bias, Wih4, Whh4, smem);
            if (taskB >= 0) {
                if (t == 0)
                    lstm_core<true>(taskB * 2, tid, xT4last, nullptr, hc, hn, cB, bias, Wih4, Whh4, smem);
                else
                    lstm_core<false>(taskB * 2, tid, nullptr, xs, hc, hn, cB, bias, Wih4, Whh4, smem);
            }
        }
        gridbar(barcnt, epoch);
        out_row(bi, tid, t, hn, ctxH + (size_t)t * 4096, Wo, bo,
                outH + (size_t)t * 16384, dout, smem);
        gridbar(barcnt, epoch);
    }
}

} // namespace

extern "C" void kernel_launch(void* const* d_in, const int* in_sizes, int n_in,
                              void* d_out, int out_size, void* d_ws, size_t ws_size,
                              hipStream_t stream)
{
    (void)in_sizes; (void)n_in; (void)out_size; (void)ws_size;
    const float* input_seq = (const float*)d_in[0];
    const float* h0     = (const float*)d_in[1];
    const float* c0     = (const float*)d_in[2];
    const float* W_ih_e = (const float*)d_in[3];
    const float* W_hh_e = (const float*)d_in[4];
    const float* b_e    = (const float*)d_in[5];
    const float* W_ih_d = (const float*)d_in[6];
    const float* W_hh_d = (const float*)d_in[7];
    const float* b_d    = (const float*)d_in[8];
    const float* We_p   = (const float*)d_in[9];
    const float* be_p   = (const float*)d_in[10];
    const float* Wh_p   = (const float*)d_in[11];
    const float* bh_p   = (const float*)d_in[12];
    const float* Wa     = (const float*)d_in[13];
    const float* ba     = (const float*)d_in[14];
    const float* v      = (const float*)d_in[15];
    const float* Wo     = (const float*)d_in[16];
    const float* bo     = (const float*)d_in[17];
    float* out = (float*)d_out;

    unsigned* barcnt = (unsigned*)d_ws;       // [0]=enc, [16]=dec
    float* ws      = (float*)d_ws + 64;
    float* xT      = ws;                      // 8388608
    float* encH    = xT + 8388608;            // 513*32768 = 16809984 (float2-packed)
    float* cT      = encH + 16809984;         // 32768
    float* We_pT   = cT + 32768;              // 32768
    float* Wh_pT   = We_pT + 32768;           // 32768
    float* WahT    = Wh_pT + 32768;           // 4096
    float* WaeT    = WahT + 4096;             // 4096
    float* encProj = WaeT + 4096;             // 2097152
    float* attnPre = encProj + 2097152;       // 2097152
    float* dechH   = attnPre + 2097152;       // 96*32768 = 3145728
    float* ctxH    = dechH + 3145728;         // 96*4096 = 393216
    float* outH    = ctxH + 393216;           // 96*16384 = 1572864

    hipMemsetAsync(d_ws, 0, 256, stream);     // zero barrier counters
    k_transpose_input<<<2048, 256, 0, stream>>>(input_seq, (float4*)xT);
    k_prep<<<544, 256, 0, stream>>>(We_p, Wh_p, h0, c0, Wa,
                                    We_pT, Wh_pT, encH, cT, WahT, WaeT);
    k_enc_persistent<<<256, 512, 0, stream>>>((const float4*)xT, encH, cT,
                                              W_ih_e, W_hh_e, b_e, barcnt);
    k_proj_attn<<<1024, 256, 0, stream>>>(encH, We_pT, be_p, WaeT, ba,
                                          encProj, attnPre);
    k_dec_persistent<<<256, 512, 0, stream>>>((const float4*)(xT + (size_t)511 * 16384),
                                              encH + (size_t)512 * 32768,
                                              dechH, cT,
                                              W_ih_d, W_hh_d, b_d,
                                              Wh_pT, bh_p, WahT, v,
                                              attnPre, encProj, ctxH,
                                              Wo, bo, outH, out, barcnt + 16);
}

// Round 5
// 13994.989 us; speedup vs baseline: 5.9195x; 1.1404x over previous
//
#include <hip/hip_runtime.h>

// Seq2seq LSTM + attention — persistent kernels, contention-free flag barrier.
//
// Round-4 bug (fixed here): xQ is float4*, one timestep = 4096 float4s; the
// overlapped x-part used stride 1024 (float-pointer leftover) => read wrong
// timestep's x from step 1 on. Single-line fix: * 4096.
//
// Barrier: arrival = sc1 STORE to flags[blockIdx] (256 distinct words);
// wait = wave0 polls all 256 flags (4/lane + __all). One hop, no RMW
// contention. All cross-block activations are written once to never-reused
// addresses via relaxed agent-scope (sc1) stores; readers use plain loads.
//
// Layouts: quad-packed feature-major: val(d, b) at [(d>>2)*256 + b*4 + (d&3)]
// so readers issue global_load_dwordx4 per 4 features.

namespace {

__device__ __forceinline__ float fsigmoid(float x) {
    return 1.0f / (1.0f + __expf(-x));
}
__device__ __forceinline__ float ftanh(float x) {
    float e = __expf(2.0f * x);
    return 1.0f - 2.0f / (e + 1.0f);
}

__device__ __forceinline__ void coh_store(float* p, float v) {
    __hip_atomic_store(p, v, __ATOMIC_RELAXED, __HIP_MEMORY_SCOPE_AGENT);
}
__device__ __forceinline__ void coh_store2(float* p, float2 v) {
    union { float2 f; unsigned long long u; } cv; cv.f = v;
    __hip_atomic_store((unsigned long long*)p, cv.u,
                       __ATOMIC_RELAXED, __HIP_MEMORY_SCOPE_AGENT);
}

// ---- contention-free barrier ---------------------------------------------
__device__ __forceinline__ void bar_arrive(unsigned* flags, int bi, unsigned val) {
    if (threadIdx.x < 64) {
        asm volatile("s_waitcnt vmcnt(0)" ::: "memory");
        if (threadIdx.x == 0)
            __hip_atomic_store(&flags[bi], val, __ATOMIC_RELAXED, __HIP_MEMORY_SCOPE_AGENT);
    }
}
__device__ __forceinline__ void bar_wait(const unsigned* flags, unsigned epoch) {
    if (threadIdx.x < 64) {
        const unsigned* f = flags + threadIdx.x * 4;
        for (;;) {
            unsigned a = __hip_atomic_load(f + 0, __ATOMIC_RELAXED, __HIP_MEMORY_SCOPE_AGENT);
            unsigned b = __hip_atomic_load(f + 1, __ATOMIC_RELAXED, __HIP_MEMORY_SCOPE_AGENT);
            unsigned c = __hip_atomic_load(f + 2, __ATOMIC_RELAXED, __HIP_MEMORY_SCOPE_AGENT);
            unsigned d = __hip_atomic_load(f + 3, __ATOMIC_RELAXED, __HIP_MEMORY_SCOPE_AGENT);
            int ok = (a >= epoch) && (b >= epoch) && (c >= epoch) && (d >= epoch);
            if (__all(ok)) break;
            __builtin_amdgcn_s_sleep(1);
        }
    }
    __syncthreads();
}

// ---- transpose input_seq (B,S,F) -> quad layout [s][f/4][b][4] -----------
__global__ __launch_bounds__(256) void k_transpose_input(
    const float* __restrict__ in, float4* __restrict__ xQ)
{
    __shared__ float tile[64][65];
    int s  = blockIdx.x >> 2;
    int f0 = (blockIdx.x & 3) * 64;
    int lane = threadIdx.x & 63;
    int r0   = threadIdx.x >> 6;
    for (int r = r0; r < 64; r += 4)
        tile[r][lane] = in[(size_t)r * (512 * 256) + s * 256 + f0 + lane];
    __syncthreads();
    for (int q = r0; q < 16; q += 4) {
        float4 vv = make_float4(tile[lane][4*q], tile[lane][4*q+1],
                                tile[lane][4*q+2], tile[lane][4*q+3]);
        xQ[((size_t)s * 64 + (f0 >> 2) + q) * 64 + lane] = vv;
    }
}

// ---- small weight/state transposes; encH slot0 quad-packed ---------------
__global__ __launch_bounds__(256) void k_prep(
    const float* __restrict__ We_p, const float* __restrict__ Wh_p,
    const float* __restrict__ h0,   const float* __restrict__ c0,
    const float* __restrict__ Wa,
    float* __restrict__ We_pT, float* __restrict__ Wh_pT,
    float* __restrict__ encH0, float* __restrict__ cT,
    float* __restrict__ WahT,  float* __restrict__ WaeT)
{
    int idx = blockIdx.x * blockDim.x + threadIdx.x;
    const int total = 32768 * 4 + 4096 * 2;
    for (; idx < total; idx += gridDim.x * blockDim.x) {
        if (idx < 32768) {
            int u = idx >> 6, h = idx & 63;
            We_pT[idx] = We_p[h * 512 + u];
        } else if (idx < 65536) {
            int i2 = idx - 32768; int k = i2 >> 6, i = i2 & 63;
            Wh_pT[i2] = Wh_p[i * 512 + k];
        } else if (idx < 98304) {
            int i2 = idx - 65536; int u = i2 >> 6, b = i2 & 63;
            encH0[(u >> 2) * 256 + b * 4 + (u & 3)] = h0[b * 512 + u];
        } else if (idx < 131072) {
            int i2 = idx - 98304; int u = i2 >> 6, b = i2 & 63;
            cT[i2] = c0[b * 512 + u];
        } else if (idx < 135168) {
            int i2 = idx - 131072; int j = i2 >> 6, i = i2 & 63;
            WahT[i2] = Wa[i * 128 + j];
        } else {
            int i2 = idx - 135168; int h2 = i2 >> 6, h = i2 & 63;
            WaeT[i2] = Wa[h * 128 + 64 + h2];
        }
    }
}

// ---- gate-GEMM accumulation over a quad segment --------------------------
template<int NQ>
__device__ __forceinline__ void accum_seg(
    float acc[8], const float4* __restrict__ actQ, int qb,
    const float4* __restrict__ W4, int wstride, int u0, int lane)
{
    #pragma unroll 4
    for (int q = qb; q < qb + NQ; ++q) {
        float4 a = actQ[q * 64 + lane];
        #pragma unroll
        for (int uu = 0; uu < 2; ++uu)
            #pragma unroll
            for (int g = 0; g < 4; ++g) {
                float4 wv = W4[(size_t)(g * 512 + u0 + uu) * wstride + q];
                float& A = acc[uu * 4 + g];
                A = fmaf(a.x, wv.x, A); A = fmaf(a.y, wv.y, A);
                A = fmaf(a.z, wv.z, A); A = fmaf(a.w, wv.w, A);
            }
    }
}

// ---- reduce partials, nonlinearity, quad-packed h store (wave0) ----------
__device__ __forceinline__ void lstm_finish(
    int u0, int tid, int w, float acc[8], float2& creg,
    const float* __restrict__ bias, float* __restrict__ houtSlot, float* smem)
{
    int lane = tid & 63;
    float* part = smem;          // [8][8][64]
    float* gsum = smem + 4096;   // [8][64]
    #pragma unroll
    for (int r = 0; r < 8; ++r)
        part[(w * 8 + r) * 64 + lane] = acc[r];
    __syncthreads();
    {
        int b = tid & 63, r = tid >> 6;
        float s = 0.f;
        #pragma unroll
        for (int ww = 0; ww < 8; ++ww)
            s += part[(ww * 8 + r) * 64 + b];
        gsum[r * 64 + b] = s;
    }
    __syncthreads();
    if (tid < 64) {
        int b = tid;
        float cc[2] = {creg.x, creg.y};
        float hv[2];
        #pragma unroll
        for (int uu = 0; uu < 2; ++uu) {
            int u = u0 + uu;
            float gi = gsum[(uu*4+0)*64 + b] + bias[u];
            float gf = gsum[(uu*4+1)*64 + b] + bias[512 + u];
            float gg = gsum[(uu*4+2)*64 + b] + bias[1024 + u];
            float go = gsum[(uu*4+3)*64 + b] + bias[1536 + u];
            float si = fsigmoid(gi), sf = fsigmoid(gf), so = fsigmoid(go);
            float tg = ftanh(gg);
            float cn = sf * cc[uu] + si * tg;
            cc[uu] = cn;
            hv[uu] = so * ftanh(cn);
        }
        creg = make_float2(cc[0], cc[1]);
        coh_store2(houtSlot + (u0 >> 2) * 256 + b * 4 + (u0 & 3),
                   make_float2(hv[0], hv[1]));
    }
}

// ---- persistent encoder: overlap x-part(t+1) with barrier ----------------
__global__ __launch_bounds__(512) void k_enc_persistent(
    const float4* __restrict__ xQ, float* __restrict__ encH,
    float* __restrict__ cT,
    const float* __restrict__ Wih, const float* __restrict__ Whh,
    const float* __restrict__ bias, unsigned* flags)
{
    __shared__ float smem[4608];
    int tid = threadIdx.x;
    int lane = tid & 63;
    int w = __builtin_amdgcn_readfirstlane(tid >> 6);
    int bi = blockIdx.x;
    int u0 = bi * 2;
    const float4* Wih4 = (const float4*)Wih;
    const float4* Whh4 = (const float4*)Whh;
    float2 creg = make_float2(0.f, 0.f);
    if (tid < 64) { creg.x = cT[u0 * 64 + tid]; creg.y = cT[(u0 + 1) * 64 + tid]; }
    float acc[8];
    #pragma unroll
    for (int r = 0; r < 8; ++r) acc[r] = 0.f;
    accum_seg<8>(acc, xQ, w * 8, Wih4, 64, u0, lane);          // x-part t=0
    for (int t = 0; t < 512; ++t) {
        bar_wait(flags, (unsigned)t);                           // h[t] ready
        accum_seg<16>(acc, (const float4*)(encH + (size_t)t * 32768),
                      w * 16, Whh4, 128, u0, lane);
        lstm_finish(u0, tid, w, acc, creg, bias,
                    encH + (size_t)(t + 1) * 32768, smem);
        bar_arrive(flags, bi, (unsigned)(t + 1));
        #pragma unroll
        for (int r = 0; r < 8; ++r) acc[r] = 0.f;
        if (t + 1 < 512)   // x-part t+1 under barrier; step stride = 4096 float4
            accum_seg<8>(acc, xQ + (size_t)(t + 1) * 4096, w * 8, Wih4, 64, u0, lane);
    }
    if (tid < 64) { cT[u0 * 64 + tid] = creg.x; cT[(u0 + 1) * 64 + tid] = creg.y; }
}

// ---- enc_proj + enc_attn (ba folded), parallel pass ----------------------
__global__ __launch_bounds__(256) void k_proj_attn(
    const float* __restrict__ encH,  const float* __restrict__ We_pT,
    const float* __restrict__ be_p,  const float* __restrict__ WaeT,
    const float* __restrict__ ba,
    float* __restrict__ encProj, float* __restrict__ attnPre)
{
    int lane = threadIdx.x & 63;
    int w    = __builtin_amdgcn_readfirstlane((int)threadIdx.x >> 6);
    int wid  = blockIdx.x * 4 + w;
    int b    = wid >> 6;
    int soct = wid & 63;
    float acc[8];
    float bep = be_p[lane];
    #pragma unroll
    for (int j = 0; j < 8; ++j) acc[j] = bep;
    #pragma unroll 2
    for (int q = 0; q < 128; ++q) {
        float w0 = We_pT[(4*q+0) * 64 + lane];
        float w1 = We_pT[(4*q+1) * 64 + lane];
        float w2 = We_pT[(4*q+2) * 64 + lane];
        float w3 = We_pT[(4*q+3) * 64 + lane];
        #pragma unroll
        for (int j = 0; j < 8; ++j) {
            const float4* hb4 = (const float4*)(encH + (size_t)(soct*8 + j + 1) * 32768);
            float4 hv = hb4[q * 64 + b];
            acc[j] = fmaf(hv.x, w0, acc[j]); acc[j] = fmaf(hv.y, w1, acc[j]);
            acc[j] = fmaf(hv.z, w2, acc[j]); acc[j] = fmaf(hv.w, w3, acc[j]);
        }
    }
    #pragma unroll
    for (int j = 0; j < 8; ++j)
        encProj[((size_t)b * 512 + soct * 8 + j) * 64 + lane] = acc[j];
    #pragma unroll
    for (int j = 0; j < 8; ++j) {
        float aa = ba[lane];
        for (int h2 = 0; h2 < 64; ++h2)
            aa = fmaf(__shfl(acc[j], h2), WaeT[h2 * 64 + lane], aa);
        attnPre[((size_t)b * 512 + soct * 8 + j) * 64 + lane] = aa;
    }
}

// ---- attention for one batch b -------------------------------------------
__device__ __forceinline__ void attention_block(
    int b, int tid, int w,
    const float* __restrict__ hcur,     // quad-packed
    const float* __restrict__ Wh_pT, const float* __restrict__ bh_p,
    const float* __restrict__ WahT,  const float* __restrict__ v,
    const float* __restrict__ attnPre, const float* __restrict__ encProj,
    float* __restrict__ ctxQ, float* smem)
{
    int lane = tid & 63;
    float* hq     = smem;
    float* hWa    = smem + 64;
    float* scores = smem + 128;
    float* part   = smem + 640;
    float* red    = smem + 1152;
    {
        const float4* h4 = (const float4*)hcur;
        float p = 0.f;
        int q0 = w * 16;
        #pragma unroll 4
        for (int q = q0; q < q0 + 16; ++q) {
            float4 hv = h4[q * 64 + b];
            p = fmaf(hv.x, Wh_pT[(4*q+0) * 64 + lane], p);
            p = fmaf(hv.y, Wh_pT[(4*q+1) * 64 + lane], p);
            p = fmaf(hv.z, Wh_pT[(4*q+2) * 64 + lane], p);
            p = fmaf(hv.w, Wh_pT[(4*q+3) * 64 + lane], p);
        }
        part[w * 64 + lane] = p;
    }
    __syncthreads();
    if (tid < 64) {
        float s = bh_p[tid];
        #pragma unroll
        for (int ww = 0; ww < 8; ++ww) s += part[ww * 64 + tid];
        hq[tid] = s;
    }
    __syncthreads();
    if (tid < 64) {
        float s = 0.f;
        for (int j = 0; j < 64; ++j)
            s = fmaf(hq[j], WahT[j * 64 + tid], s);
        hWa[tid] = s;
    }
    __syncthreads();
    {
        float hw = hWa[lane];
        float vv = v[lane];
        for (int s2 = w; s2 < 512; s2 += 8) {
            float e = ftanh(hw + attnPre[((size_t)b * 512 + s2) * 64 + lane]) * vv;
            #pragma unroll
            for (int off = 32; off > 0; off >>= 1)
                e += __shfl_down(e, off);
            if (lane == 0) scores[s2] = e;
        }
    }
    __syncthreads();
    float sc = scores[tid];
    float m = sc;
    #pragma unroll
    for (int off = 32; off > 0; off >>= 1)
        m = fmaxf(m, __shfl_xor(m, off));
    if (lane == 0) red[w] = m;
    __syncthreads();
    if (tid == 0) {
        float mm = red[0];
        for (int ww = 1; ww < 8; ++ww) mm = fmaxf(mm, red[ww]);
        red[8] = mm;
    }
    __syncthreads();
    float M = red[8];
    float ex = __expf(sc - M);
    scores[tid] = ex;
    float ssum = ex;
    #pragma unroll
    for (int off = 32; off > 0; off >>= 1)
        ssum += __shfl_xor(ssum, off);
    if (lane == 0) red[w] = ssum;
    __syncthreads();
    if (tid == 0) {
        float tt = 0.f;
        for (int ww = 0; ww < 8; ++ww) tt += red[ww];
        red[8] = 1.0f / tt;
    }
    __syncthreads();
    float inv = red[8];
    {
        float a = 0.f;
        for (int s2 = w; s2 < 512; s2 += 8)
            a = fmaf(scores[s2], encProj[((size_t)b * 512 + s2) * 64 + lane], a);
        part[w * 64 + lane] = a;
    }
    __syncthreads();
    if (tid < 64) {
        float s = 0.f;
        #pragma unroll
        for (int ww = 0; ww < 8; ++ww) s += part[ww * 64 + tid];
        coh_store(&ctxQ[(tid >> 2) * 256 + b * 4 + (tid & 3)], s * inv);
    }
}

// ---- output row f: quad-packed write to outH -----------------------------
__device__ __forceinline__ void out_row(
    int f, int tid, int w, int t,
    const float* __restrict__ hn,   // quad-packed
    const float* __restrict__ ctxQ, // quad-packed
    const float* __restrict__ Wo, const float* __restrict__ bo,
    float* __restrict__ outQ, float* __restrict__ dout, float* smem)
{
    int lane = tid & 63;
    const float4* W4 = (const float4*)(Wo + (size_t)f * 576);
    const float4* h4 = (const float4*)hn;
    const float4* c4 = (const float4*)ctxQ;
    float acc = 0.f;
    int k0 = w * 72;
    #pragma unroll 2
    for (int k = k0; k < k0 + 72; k += 4) {
        float4 wv = W4[k >> 2];
        float4 a = (k < 512) ? h4[(k >> 2) * 64 + lane]
                             : c4[((k - 512) >> 2) * 64 + lane];
        acc = fmaf(a.x, wv.x, acc); acc = fmaf(a.y, wv.y, acc);
        acc = fmaf(a.z, wv.z, acc); acc = fmaf(a.w, wv.w, acc);
    }
    smem[w * 64 + lane] = acc;
    __syncthreads();
    if (tid < 64) {
        float s = bo[f];
        #pragma unroll
        for (int ww = 0; ww < 8; ++ww) s += smem[ww * 64 + tid];
        coh_store(&outQ[(f >> 2) * 256 + tid * 4 + (f & 3)], s);
        if (f == 255) dout[tid * 96 + t] = s;
    }
}

// ---- decoder LSTM task ----------------------------------------------------
__device__ __forceinline__ void dec_lstm_task(
    int u0, int tid, int w, int lane,
    const float4* __restrict__ xq, const float* __restrict__ hc,
    float* __restrict__ hn, float2& creg,
    const float4* __restrict__ Wih4, const float4* __restrict__ Whh4,
    const float* __restrict__ bias, float* smem)
{
    float acc[8];
    #pragma unroll
    for (int r = 0; r < 8; ++r) acc[r] = 0.f;
    accum_seg<8>(acc, xq, w * 8, Wih4, 64, u0, lane);
    accum_seg<16>(acc, (const float4*)hc, w * 16, Whh4, 128, u0, lane);
    lstm_finish(u0, tid, w, acc, creg, bias, hn, smem);
}

// ---- persistent decoder ---------------------------------------------------
__global__ __launch_bounds__(512) void k_dec_persistent(
    const float4* __restrict__ xQlast,
    const float* __restrict__ encHend,
    float* __restrict__ dechH,            // [96][quad 32768]
    float* __restrict__ cT,
    const float* __restrict__ Wih, const float* __restrict__ Whh,
    const float* __restrict__ bias,
    const float* __restrict__ Wh_pT, const float* __restrict__ bh_p,
    const float* __restrict__ WahT,  const float* __restrict__ v,
    const float* __restrict__ attnPre, const float* __restrict__ encProj,
    float* __restrict__ ctxH,             // [96][quad 4096]
    const float* __restrict__ Wo, const float* __restrict__ bo,
    float* __restrict__ outH,             // [96][quad 16384]
    float* __restrict__ dout, unsigned* flags)
{
    __shared__ float smem[4608];
    int tid = threadIdx.x;
    int lane = tid & 63;
    int w = __builtin_amdgcn_readfirstlane(tid >> 6);
    int bi = blockIdx.x;
    const float4* Wih4 = (const float4*)Wih;
    const float4* Whh4 = (const float4*)Whh;
    int taskA = -1, taskB = -1;
    if (bi >= 64) { taskA = bi - 64; if (bi < 128) taskB = bi + 128; }
    float2 cA = make_float2(0.f, 0.f), cB = cA;
    if (taskA >= 0 && tid < 64) {
        int u0 = taskA * 2;
        cA.x = cT[u0 * 64 + tid]; cA.y = cT[(u0 + 1) * 64 + tid];
    }
    if (taskB >= 0 && tid < 64) {
        int u0 = taskB * 2;
        cB.x = cT[u0 * 64 + tid]; cB.y = cT[(u0 + 1) * 64 + tid];
    }
    for (int t = 0; t < 96; ++t) {
        bar_wait(flags, (unsigned)(2 * t));     // h[t-1], out[t-1] visible
        const float* hc = t ? dechH + (size_t)(t - 1) * 32768 : encHend;
        float* hn = dechH + (size_t)t * 32768;
        const float4* xq = t ? (const float4*)(outH + (size_t)(t - 1) * 16384) : xQlast;
        if (bi < 64) {
            attention_block(bi, tid, w, hc, Wh_pT, bh_p, WahT, v,
                            attnPre, encProj, ctxH + (size_t)t * 4096, smem);
        } else {
            dec_lstm_task(taskA * 2, tid, w, lane, xq, hc, hn, cA, Wih4, Whh4, bias, smem);
            if (taskB >= 0)
                dec_lstm_task(taskB * 2, tid, w, lane, xq, hc, hn, cB, Wih4, Whh4, bias, smem);
        }
        bar_arrive(flags, bi, (unsigned)(2 * t + 1));
        bar_wait(flags, (unsigned)(2 * t + 1));  // hn, ctx visible
        out_row(bi, tid, w, t, hn, ctxH + (size_t)t * 4096, Wo, bo,
                outH + (size_t)t * 16384, dout, smem);
        bar_arrive(flags, bi, (unsigned)(2 * t + 2));
    }
}

} // namespace

extern "C" void kernel_launch(void* const* d_in, const int* in_sizes, int n_in,
                              void* d_out, int out_size, void* d_ws, size_t ws_size,
                              hipStream_t stream)
{
    (void)in_sizes; (void)n_in; (void)out_size; (void)ws_size;
    const float* input_seq = (const float*)d_in[0];
    const float* h0     = (const float*)d_in[1];
    const float* c0     = (const float*)d_in[2];
    const float* W_ih_e = (const float*)d_in[3];
    const float* W_hh_e = (const float*)d_in[4];
    const float* b_e    = (const float*)d_in[5];
    const float* W_ih_d = (const float*)d_in[6];
    const float* W_hh_d = (const float*)d_in[7];
    const float* b_d    = (const float*)d_in[8];
    const float* We_p   = (const float*)d_in[9];
    const float* be_p   = (const float*)d_in[10];
    const float* Wh_p   = (const float*)d_in[11];
    const float* bh_p   = (const float*)d_in[12];
    const float* Wa     = (const float*)d_in[13];
    const float* ba     = (const float*)d_in[14];
    const float* v      = (const float*)d_in[15];
    const float* Wo     = (const float*)d_in[16];
    const float* bo     = (const float*)d_in[17];
    float* out = (float*)d_out;

    unsigned* encFlags = (unsigned*)d_ws;       // 256 words
    unsigned* decFlags = encFlags + 256;        // 256 words
    float* ws      = (float*)d_ws + 1024;       // 4KB offset
    float* xT      = ws;                        // 8388608
    float* encH    = xT + 8388608;              // 513*32768
    float* cT      = encH + 16809984;           // 32768
    float* We_pT   = cT + 32768;                // 32768
    float* Wh_pT   = We_pT + 32768;             // 32768
    float* WahT    = Wh_pT + 32768;             // 4096
    float* WaeT    = WahT + 4096;               // 4096
    float* encProj = WaeT + 4096;               // 2097152
    float* attnPre = encProj + 2097152;         // 2097152
    float* dechH   = attnPre + 2097152;         // 96*32768
    float* ctxH    = dechH + 3145728;           // 96*4096
    float* outH    = ctxH + 393216;             // 96*16384

    hipMemsetAsync(d_ws, 0, 4096, stream);      // zero barrier flags
    k_transpose_input<<<2048, 256, 0, stream>>>(input_seq, (float4*)xT);
    k_prep<<<544, 256, 0, stream>>>(We_p, Wh_p, h0, c0, Wa,
                                    We_pT, Wh_pT, encH, cT, WahT, WaeT);
    k_enc_persistent<<<256, 512, 0, stream>>>((const float4*)xT, encH, cT,
                                              W_ih_e, W_hh_e, b_e, encFlags);
    k_proj_attn<<<1024, 256, 0, stream>>>(encH, We_pT, be_p, WaeT, ba,
                                          encProj, attnPre);
    k_dec_persistent<<<256, 512, 0, stream>>>((const float4*)(xT + (size_t)511 * 16384),
                                              encH + (size_t)512 * 32768,
                                              dechH, cT,
                                              W_ih_d, W_hh_d, b_d,
                                              Wh_pT, bh_p, WahT, v,
                                              attnPre, encProj, ctxH,
                                              Wo, bo, outH, out, decFlags);
}

// Round 8
// 9941.511 us; speedup vs baseline: 8.3331x; 1.4077x over previous
//
#include <hip/hip_runtime.h>

// Seq2seq LSTM + attention — persistent kernels, contention-free flag barrier.
//
// Decoder: fold Wo into the recurrent weights:
//   x_t = out_{t-1} = Wo.[h_t; ctx_{t-1}] + bo  =>
//   gates_t = W_h.h_t + W_c.ctx_{t-1} + b'   (t>=1)
//   W_h = Wih_d.Wo[:, :512] + Whh_d ; W_c = Wih_d.Wo[:, 512:] ; b' = b_d + Wih_d.bo
//   t=0: gates = Whh_d.h0 + g0,  g0 = Wih_d.x_last + b_d.
// ONE barrier/step. Prediction column computed post-hoc by k_dout from the
// stored h/ctx histories (no in-loop output work at all).
//
// Compiler-crash de-risking (rounds 6/7 segfaulted clang): no null-selected
// operands in lstm_finish (two branch-free variants), no __syncthreads under
// divergent block-id branches beyond the round-5-proven attention shape, no
// post-loop barrier epilogue, k_proj_attn reverted to the round-5 form and
// the [b][h][s] transpose done by a separate simple tile-transpose kernel.
// attnPreT aliases the dead xT region (xT unused after encoder/g0 prep).

namespace {

__device__ __forceinline__ float fsigmoid(float x) {
    return 1.0f / (1.0f + __expf(-x));
}
__device__ __forceinline__ float ftanh(float x) {
    float e = __expf(2.0f * x);
    return 1.0f - 2.0f / (e + 1.0f);
}

__device__ __forceinline__ void coh_store(float* p, float v) {
    __hip_atomic_store(p, v, __ATOMIC_RELAXED, __HIP_MEMORY_SCOPE_AGENT);
}
__device__ __forceinline__ void coh_store2(float* p, float2 v) {
    union { float2 f; unsigned long long u; } cv; cv.f = v;
    __hip_atomic_store((unsigned long long*)p, cv.u,
                       __ATOMIC_RELAXED, __HIP_MEMORY_SCOPE_AGENT);
}

// ---- contention-free barrier ---------------------------------------------
__device__ __forceinline__ void bar_arrive(unsigned* flags, int bi, unsigned val) {
    if (threadIdx.x < 64) {
        asm volatile("s_waitcnt vmcnt(0)" ::: "memory");
        if (threadIdx.x == 0)
            __hip_atomic_store(&flags[bi], val, __ATOMIC_RELAXED, __HIP_MEMORY_SCOPE_AGENT);
    }
}
__device__ __forceinline__ void bar_wait(const unsigned* flags, unsigned epoch) {
    if (threadIdx.x < 64) {
        const unsigned* f = flags + threadIdx.x * 4;
        for (;;) {
            unsigned a = __hip_atomic_load(f + 0, __ATOMIC_RELAXED, __HIP_MEMORY_SCOPE_AGENT);
            unsigned b = __hip_atomic_load(f + 1, __ATOMIC_RELAXED, __HIP_MEMORY_SCOPE_AGENT);
            unsigned c = __hip_atomic_load(f + 2, __ATOMIC_RELAXED, __HIP_MEMORY_SCOPE_AGENT);
            unsigned d = __hip_atomic_load(f + 3, __ATOMIC_RELAXED, __HIP_MEMORY_SCOPE_AGENT);
            int ok = (a >= epoch) && (b >= epoch) && (c >= epoch) && (d >= epoch);
            if (__all(ok)) break;
            __builtin_amdgcn_s_sleep(1);
        }
    }
    __syncthreads();
}

// ---- transpose input_seq (B,S,F) -> quad layout [s][f/4][b][4] -----------
__global__ __launch_bounds__(256) void k_transpose_input(
    const float* __restrict__ in, float4* __restrict__ xQ)
{
    __shared__ float tile[64][65];
    int s  = blockIdx.x >> 2;
    int f0 = (blockIdx.x & 3) * 64;
    int lane = threadIdx.x & 63;
    int r0   = threadIdx.x >> 6;
    for (int r = r0; r < 64; r += 4)
        tile[r][lane] = in[(size_t)r * (512 * 256) + s * 256 + f0 + lane];
    __syncthreads();
    for (int q = r0; q < 16; q += 4) {
        float4 vv = make_float4(tile[lane][4*q], tile[lane][4*q+1],
                                tile[lane][4*q+2], tile[lane][4*q+3]);
        xQ[((size_t)s * 64 + (f0 >> 2) + q) * 64 + lane] = vv;
    }
}

// ---- small weight/state transposes; encH slot0 quad-packed ---------------
__global__ __launch_bounds__(256) void k_prep(
    const float* __restrict__ We_p, const float* __restrict__ Wh_p,
    const float* __restrict__ h0,   const float* __restrict__ c0,
    const float* __restrict__ Wa,
    float* __restrict__ We_pT, float* __restrict__ Wh_pT,
    float* __restrict__ encH0, float* __restrict__ cT,
    float* __restrict__ WahT,  float* __restrict__ WaeT)
{
    int idx = blockIdx.x * blockDim.x + threadIdx.x;
    const int total = 32768 * 4 + 4096 * 2;
    for (; idx < total; idx += gridDim.x * blockDim.x) {
        if (idx < 32768) {
            int u = idx >> 6, h = idx & 63;
            We_pT[idx] = We_p[h * 512 + u];
        } else if (idx < 65536) {
            int i2 = idx - 32768; int k = i2 >> 6, i = i2 & 63;
            Wh_pT[i2] = Wh_p[i * 512 + k];
        } else if (idx < 98304) {
            int i2 = idx - 65536; int u = i2 >> 6, b = i2 & 63;
            encH0[(u >> 2) * 256 + b * 4 + (u & 3)] = h0[b * 512 + u];
        } else if (idx < 131072) {
            int i2 = idx - 98304; int u = i2 >> 6, b = i2 & 63;
            cT[i2] = c0[b * 512 + u];
        } else if (idx < 135168) {
            int i2 = idx - 131072; int j = i2 >> 6, i = i2 & 63;
            WahT[i2] = Wa[i * 128 + j];
        } else {
            int i2 = idx - 135168; int h2 = i2 >> 6, h = i2 & 63;
            WaeT[i2] = Wa[h * 128 + 64 + h2];
        }
    }
}

// ---- W_h = Wih_d.Wo[:, :512] + Whh_d ; W_c = Wih_d.Wo[:, 512:] ; b' ------
__global__ __launch_bounds__(256) void k_prep_wcomb(
    const float* __restrict__ Wih, const float* __restrict__ Whh,
    const float* __restrict__ Wo,  const float* __restrict__ bd,
    const float* __restrict__ bo,
    float* __restrict__ Wh, float* __restrict__ Wc, float* __restrict__ bprime)
{
    int r = blockIdx.x;          // 0..2047
    for (int j = threadIdx.x; j < 576; j += 256) {
        float acc = 0.f;
        for (int f = 0; f < 256; ++f)
            acc = fmaf(Wih[r * 256 + f], Wo[f * 576 + j], acc);
        if (j < 512) Wh[(size_t)r * 512 + j] = acc + Whh[(size_t)r * 512 + j];
        else         Wc[(size_t)r * 64 + (j - 512)] = acc;
    }
    if (threadIdx.x == 0) {
        float s = bd[r];
        for (int f = 0; f < 256; ++f)
            s = fmaf(Wih[r * 256 + f], bo[f], s);
        bprime[r] = s;
    }
}

// ---- g0[r][b] = Wih_d . x_last + b_d -------------------------------------
__global__ __launch_bounds__(256) void k_prep_g0(
    const float4* __restrict__ xQlast, const float* __restrict__ Wih,
    const float* __restrict__ bd, float* __restrict__ g0)
{
    int r = blockIdx.x * 4 + ((int)threadIdx.x >> 6);
    int lane = threadIdx.x & 63;
    const float4* Wih4 = (const float4*)Wih;
    float acc = bd[r];
    for (int q = 0; q < 64; ++q) {
        float4 a  = xQlast[q * 64 + lane];
        float4 wv = Wih4[(size_t)r * 64 + q];
        acc = fmaf(a.x, wv.x, acc); acc = fmaf(a.y, wv.y, acc);
        acc = fmaf(a.z, wv.z, acc); acc = fmaf(a.w, wv.w, acc);
    }
    g0[(size_t)r * 64 + lane] = acc;
}

// ---- gate-GEMM accumulation over a quad segment (NQ = 8 or 16 only) ------
template<int NQ>
__device__ __forceinline__ void accum_seg(
    float acc[8], const float4* __restrict__ actQ, int qb,
    const float4* __restrict__ W4, int wstride, int u0, int lane)
{
    #pragma unroll 4
    for (int q = qb; q < qb + NQ; ++q) {
        float4 a = actQ[q * 64 + lane];
        #pragma unroll
        for (int uu = 0; uu < 2; ++uu)
            #pragma unroll
            for (int g = 0; g < 4; ++g) {
                float4 wv = W4[(size_t)(g * 512 + u0 + uu) * wstride + q];
                float& A = acc[uu * 4 + g];
                A = fmaf(a.x, wv.x, A); A = fmaf(a.y, wv.y, A);
                A = fmaf(a.z, wv.z, A); A = fmaf(a.w, wv.w, A);
            }
    }
}

// ---- ctx-part accumulation: 2 quads per wave -----------------------------
__device__ __forceinline__ void accum_ctx(
    float acc[8], const float4* __restrict__ c4,
    const float4* __restrict__ Wc4, int u0, int w, int lane)
{
    for (int q = w * 2; q < w * 2 + 2; ++q) {
        float4 a = c4[q * 64 + lane];
        #pragma unroll
        for (int uu = 0; uu < 2; ++uu)
            #pragma unroll
            for (int g = 0; g < 4; ++g) {
                float4 wv = Wc4[(size_t)(g * 512 + u0 + uu) * 16 + q];
                float& A = acc[uu * 4 + g];
                A = fmaf(a.x, wv.x, A); A = fmaf(a.y, wv.y, A);
                A = fmaf(a.z, wv.z, A); A = fmaf(a.w, wv.w, A);
            }
    }
}

// ---- finish variant 1: additive = per-row vector (bias / b') -------------
__device__ __forceinline__ void lstm_finish_vec(
    int u0, int tid, int w, float acc[8], float2& creg,
    const float* __restrict__ addVec, float* __restrict__ houtSlot, float* smem)
{
    int lane = tid & 63;
    float* part = smem;          // [8][8][64]
    float* gsum = smem + 4096;   // [8][64]
    #pragma unroll
    for (int r = 0; r < 8; ++r)
        part[(w * 8 + r) * 64 + lane] = acc[r];
    __syncthreads();
    {
        int b = tid & 63, r = tid >> 6;
        float s = 0.f;
        #pragma unroll
        for (int ww = 0; ww < 8; ++ww)
            s += part[(ww * 8 + r) * 64 + b];
        gsum[r * 64 + b] = s;
    }
    __syncthreads();
    if (tid < 64) {
        int b = tid;
        float cc[2] = {creg.x, creg.y};
        float hv[2];
        #pragma unroll
        for (int uu = 0; uu < 2; ++uu) {
            int u = u0 + uu;
            float gi = gsum[(uu*4+0)*64 + b] + addVec[u];
            float gf = gsum[(uu*4+1)*64 + b] + addVec[512 + u];
            float gg = gsum[(uu*4+2)*64 + b] + addVec[1024 + u];
            float go = gsum[(uu*4+3)*64 + b] + addVec[1536 + u];
            float si = fsigmoid(gi), sf = fsigmoid(gf), so = fsigmoid(go);
            float tg = ftanh(gg);
            float cn = sf * cc[uu] + si * tg;
            cc[uu] = cn;
            hv[uu] = so * ftanh(cn);
        }
        creg = make_float2(cc[0], cc[1]);
        coh_store2(houtSlot + (u0 >> 2) * 256 + b * 4 + (u0 & 3),
                   make_float2(hv[0], hv[1]));
    }
}

// ---- finish variant 2: additive = row x batch buffer (g0) ----------------
__device__ __forceinline__ void lstm_finish_row(
    int u0, int tid, int w, float acc[8], float2& creg,
    const float* __restrict__ addRowB, float* __restrict__ houtSlot, float* smem)
{
    int lane = tid & 63;
    float* part = smem;
    float* gsum = smem + 4096;
    #pragma unroll
    for (int r = 0; r < 8; ++r)
        part[(w * 8 + r) * 64 + lane] = acc[r];
    __syncthreads();
    {
        int b = tid & 63, r = tid >> 6;
        float s = 0.f;
        #pragma unroll
        for (int ww = 0; ww < 8; ++ww)
            s += part[(ww * 8 + r) * 64 + b];
        gsum[r * 64 + b] = s;
    }
    __syncthreads();
    if (tid < 64) {
        int b = tid;
        float cc[2] = {creg.x, creg.y};
        float hv[2];
        #pragma unroll
        for (int uu = 0; uu < 2; ++uu) {
            int u = u0 + uu;
            float gi = gsum[(uu*4+0)*64 + b] + addRowB[(size_t)(0 * 512 + u) * 64 + b];
            float gf = gsum[(uu*4+1)*64 + b] + addRowB[(size_t)(1 * 512 + u) * 64 + b];
            float gg = gsum[(uu*4+2)*64 + b] + addRowB[(size_t)(2 * 512 + u) * 64 + b];
            float go = gsum[(uu*4+3)*64 + b] + addRowB[(size_t)(3 * 512 + u) * 64 + b];
            float si = fsigmoid(gi), sf = fsigmoid(gf), so = fsigmoid(go);
            float tg = ftanh(gg);
            float cn = sf * cc[uu] + si * tg;
            cc[uu] = cn;
            hv[uu] = so * ftanh(cn);
        }
        creg = make_float2(cc[0], cc[1]);
        coh_store2(houtSlot + (u0 >> 2) * 256 + b * 4 + (u0 & 3),
                   make_float2(hv[0], hv[1]));
    }
}

// ---- persistent encoder: overlap x-part(t+1) with barrier ----------------
__global__ __launch_bounds__(512) void k_enc_persistent(
    const float4* __restrict__ xQ, float* __restrict__ encH,
    float* __restrict__ cT,
    const float* __restrict__ Wih, const float* __restrict__ Whh,
    const float* __restrict__ bias, unsigned* flags)
{
    __shared__ float smem[4608];
    int tid = threadIdx.x;
    int lane = tid & 63;
    int w = __builtin_amdgcn_readfirstlane(tid >> 6);
    int bi = blockIdx.x;
    int u0 = bi * 2;
    const float4* Wih4 = (const float4*)Wih;
    const float4* Whh4 = (const float4*)Whh;
    float2 creg = make_float2(0.f, 0.f);
    if (tid < 64) { creg.x = cT[u0 * 64 + tid]; creg.y = cT[(u0 + 1) * 64 + tid]; }
    float acc[8];
    #pragma unroll
    for (int r = 0; r < 8; ++r) acc[r] = 0.f;
    accum_seg<8>(acc, xQ, w * 8, Wih4, 64, u0, lane);          // x-part t=0
    for (int t = 0; t < 512; ++t) {
        bar_wait(flags, (unsigned)t);                           // h[t] ready
        accum_seg<16>(acc, (const float4*)(encH + (size_t)t * 32768),
                      w * 16, Whh4, 128, u0, lane);
        lstm_finish_vec(u0, tid, w, acc, creg, bias,
                        encH + (size_t)(t + 1) * 32768, smem);
        bar_arrive(flags, bi, (unsigned)(t + 1));
        #pragma unroll
        for (int r = 0; r < 8; ++r) acc[r] = 0.f;
        if (t + 1 < 512)   // x-part t+1 under barrier; step stride = 4096 float4
            accum_seg<8>(acc, xQ + (size_t)(t + 1) * 4096, w * 8, Wih4, 64, u0, lane);
    }
    if (tid < 64) { cT[u0 * 64 + tid] = creg.x; cT[(u0 + 1) * 64 + tid] = creg.y; }
}

// ---- enc_proj + enc_attn (ba folded), round-5 form -----------------------
__global__ __launch_bounds__(256) void k_proj_attn(
    const float* __restrict__ encH,  const float* __restrict__ We_pT,
    const float* __restrict__ be_p,  const float* __restrict__ WaeT,
    const float* __restrict__ ba,
    float* __restrict__ encProj, float* __restrict__ attnPre)
{
    int lane = threadIdx.x & 63;
    int w    = __builtin_amdgcn_readfirstlane((int)threadIdx.x >> 6);
    int wid  = blockIdx.x * 4 + w;
    int b    = wid >> 6;
    int soct = wid & 63;
    float acc[8];
    float bep = be_p[lane];
    #pragma unroll
    for (int j = 0; j < 8; ++j) acc[j] = bep;
    #pragma unroll 2
    for (int q = 0; q < 128; ++q) {
        float w0 = We_pT[(4*q+0) * 64 + lane];
        float w1 = We_pT[(4*q+1) * 64 + lane];
        float w2 = We_pT[(4*q+2) * 64 + lane];
        float w3 = We_pT[(4*q+3) * 64 + lane];
        #pragma unroll
        for (int j = 0; j < 8; ++j) {
            const float4* hb4 = (const float4*)(encH + (size_t)(soct*8 + j + 1) * 32768);
            float4 hv = hb4[q * 64 + b];
            acc[j] = fmaf(hv.x, w0, acc[j]); acc[j] = fmaf(hv.y, w1, acc[j]);
            acc[j] = fmaf(hv.z, w2, acc[j]); acc[j] = fmaf(hv.w, w3, acc[j]);
        }
    }
    #pragma unroll
    for (int j = 0; j < 8; ++j)
        encProj[((size_t)b * 512 + soct * 8 + j) * 64 + lane] = acc[j];
    #pragma unroll
    for (int j = 0; j < 8; ++j) {
        float aa = ba[lane];
        for (int h2 = 0; h2 < 64; ++h2)
            aa = fmaf(__shfl(acc[j], h2), WaeT[h2 * 64 + lane], aa);
        attnPre[((size_t)b * 512 + soct * 8 + j) * 64 + lane] = aa;
    }
}

// ---- attnPre [b][s][h] -> attnPreT [b][h][s] (tile transpose) ------------
__global__ __launch_bounds__(256) void k_attn_transpose(
    const float* __restrict__ attnPre, float* __restrict__ attnPreT)
{
    __shared__ float tile[64][65];
    int b  = blockIdx.x >> 3;        // 0..63
    int s0 = (blockIdx.x & 7) * 64;  // 0..448
    int lane = threadIdx.x & 63;
    int r0   = threadIdx.x >> 6;
    for (int r = r0; r < 64; r += 4)
        tile[r][lane] = attnPre[(size_t)b * 32768 + (size_t)(s0 + r) * 64 + lane];
    __syncthreads();
    for (int r = r0; r < 64; r += 4)
        attnPreT[(size_t)b * 32768 + (size_t)r * 512 + s0 + lane] = tile[lane][r];
}

// ---- attention for one batch b -------------------------------------------
__device__ __forceinline__ void attention_block(
    int b, int tid, int w,
    const float* __restrict__ hcur,     // quad-packed
    const float* __restrict__ Wh_pT, const float* __restrict__ bh_p,
    const float* __restrict__ WahT,  const float* __restrict__ v,
    const float* __restrict__ attnPreT, const float* __restrict__ encProj,
    float* __restrict__ ctxQ, float* smem)
{
    int lane = tid & 63;
    float* hq     = smem;
    float* hWa    = smem + 64;
    float* scores = smem + 128;   // 512
    float* part   = smem + 640;   // 512
    float* red    = smem + 1152;  // 16
    // p1: hq = Wh_p.h + bh_p
    {
        const float4* h4 = (const float4*)hcur;
        float p = 0.f;
        int q0 = w * 16;
        #pragma unroll 4
        for (int q = q0; q < q0 + 16; ++q) {
            float4 hv = h4[q * 64 + b];
            p = fmaf(hv.x, Wh_pT[(4*q+0) * 64 + lane], p);
            p = fmaf(hv.y, Wh_pT[(4*q+1) * 64 + lane], p);
            p = fmaf(hv.z, Wh_pT[(4*q+2) * 64 + lane], p);
            p = fmaf(hv.w, Wh_pT[(4*q+3) * 64 + lane], p);
        }
        part[w * 64 + lane] = p;
    }
    __syncthreads();
    if (tid < 64) {
        float s = bh_p[tid];
        #pragma unroll
        for (int ww = 0; ww < 8; ++ww) s += part[ww * 64 + tid];
        hq[tid] = s;
    }
    __syncthreads();
    // p2: hWa = Wa_h.hq
    if (tid < 64) {
        float s = 0.f;
        for (int j = 0; j < 64; ++j)
            s = fmaf(hq[j], WahT[j * 64 + tid], s);
        hWa[tid] = s;
    }
    __syncthreads();
    // p3: scores — lane owns s = w*64+lane; 64 independent coalesced loads
    {
        const float* apT = attnPreT + (size_t)b * 32768 + (w * 64 + lane);
        float acc = 0.f;
        for (int h = 0; h < 64; ++h) {
            float e = ftanh(hWa[h] + apT[(size_t)h * 512]);
            acc = fmaf(v[h], e, acc);
        }
        scores[w * 64 + lane] = acc;
    }
    __syncthreads();
    // softmax over 512
    float sc = scores[tid];
    float m = sc;
    #pragma unroll
    for (int off = 32; off > 0; off >>= 1)
        m = fmaxf(m, __shfl_xor(m, off));
    if (lane == 0) red[w] = m;
    __syncthreads();
    if (tid == 0) {
        float mm = red[0];
        for (int ww = 1; ww < 8; ++ww) mm = fmaxf(mm, red[ww]);
        red[8] = mm;
    }
    __syncthreads();
    float M = red[8];
    float ex = __expf(sc - M);
    scores[tid] = ex;
    float ssum = ex;
    #pragma unroll
    for (int off = 32; off > 0; off >>= 1)
        ssum += __shfl_xor(ssum, off);
    if (lane == 0) red[w] = ssum;
    __syncthreads();
    if (tid == 0) {
        float tt2 = 0.f;
        for (int ww = 0; ww < 8; ++ww) tt2 += red[ww];
        red[8] = 1.0f / tt2;
    }
    __syncthreads();
    float inv = red[8];
    // p5: ctx — wave w covers s in [w*64, w*64+64), 4 independent acc chains
    {
        const float* ep = encProj + ((size_t)b * 512 + w * 64) * 64 + lane;
        float ac0 = 0.f, ac1 = 0.f, ac2 = 0.f, ac3 = 0.f;
        for (int i = 0; i < 64; i += 4) {
            ac0 = fmaf(scores[w * 64 + i + 0], ep[(size_t)(i + 0) * 64], ac0);
            ac1 = fmaf(scores[w * 64 + i + 1], ep[(size_t)(i + 1) * 64], ac1);
            ac2 = fmaf(scores[w * 64 + i + 2], ep[(size_t)(i + 2) * 64], ac2);
            ac3 = fmaf(scores[w * 64 + i + 3], ep[(size_t)(i + 3) * 64], ac3);
        }
        part[w * 64 + lane] = (ac0 + ac1) + (ac2 + ac3);
    }
    __syncthreads();
    if (tid < 64) {
        float s = 0.f;
        #pragma unroll
        for (int ww = 0; ww < 8; ++ww) s += part[ww * 64 + tid];
        coh_store(&ctxQ[(tid >> 2) * 256 + b * 4 + (tid & 3)], s * inv);
    }
}

// ---- decoder LSTM task (fused weights) -----------------------------------
__device__ __forceinline__ void dec_lstm_task(
    int u0, int t, int tid, int w, int lane,
    const float* __restrict__ hc, const float* __restrict__ ctxPrev,
    float* __restrict__ hn, float2& creg,
    const float4* __restrict__ Whh4, const float4* __restrict__ Wh4,
    const float4* __restrict__ Wc4,
    const float* __restrict__ g0, const float* __restrict__ bprime,
    float* smem)
{
    float acc[8];
    #pragma unroll
    for (int r = 0; r < 8; ++r) acc[r] = 0.f;
    if (t == 0) {
        accum_seg<16>(acc, (const float4*)hc, w * 16, Whh4, 128, u0, lane);
        lstm_finish_row(u0, tid, w, acc, creg, g0, hn, smem);
    } else {
        accum_seg<16>(acc, (const float4*)hc, w * 16, Wh4, 128, u0, lane);
        accum_ctx(acc, (const float4*)ctxPrev, Wc4, u0, w, lane);
        lstm_finish_vec(u0, tid, w, acc, creg, bprime, hn, smem);
    }
}

// ---- persistent decoder: 96 steps, ONE barrier each ----------------------
__global__ __launch_bounds__(512) void k_dec_persistent(
    const float* __restrict__ encHend,
    float* __restrict__ dechH,            // [96][quad 32768]
    float* __restrict__ cT,
    const float* __restrict__ Whh,        // t=0 h-part
    const float* __restrict__ Wh,         // t>=1 fused h-part
    const float* __restrict__ Wc,         // ctx part
    const float* __restrict__ g0, const float* __restrict__ bprime,
    const float* __restrict__ Wh_pT, const float* __restrict__ bh_p,
    const float* __restrict__ WahT,  const float* __restrict__ v,
    const float* __restrict__ attnPreT, const float* __restrict__ encProj,
    float* __restrict__ ctxH,             // [96][quad 4096]
    unsigned* flags)
{
    __shared__ float smem[4608];
    int tid = threadIdx.x;
    int lane = tid & 63;
    int w = __builtin_amdgcn_readfirstlane(tid >> 6);
    int bi = blockIdx.x;
    const float4* Whh4 = (const float4*)Whh;
    const float4* Wh4  = (const float4*)Wh;
    const float4* Wc4  = (const float4*)Wc;
    int taskA = -1, taskB = -1;
    if (bi >= 64) { taskA = bi - 64; if (bi < 128) taskB = bi + 128; }
    float2 cA = make_float2(0.f, 0.f), cB = cA;
    if (taskA >= 0 && tid < 64) {
        int u0 = taskA * 2;
        cA.x = cT[u0 * 64 + tid]; cA.y = cT[(u0 + 1) * 64 + tid];
    }
    if (taskB >= 0 && tid < 64) {
        int u0 = taskB * 2;
        cB.x = cT[u0 * 64 + tid]; cB.y = cT[(u0 + 1) * 64 + tid];
    }
    for (int t = 0; t < 96; ++t) {
        bar_wait(flags, (unsigned)t);       // h^{(t)}, ctx^{(t-1)} visible
        const float* hc = t ? dechH + (size_t)(t - 1) * 32768 : encHend;
        const float* cp = t ? ctxH + (size_t)(t - 1) * 4096 : ctxH;
        if (bi < 64) {
            attention_block(bi, tid, w, hc, Wh_pT, bh_p, WahT, v,
                            attnPreT, encProj, ctxH + (size_t)t * 4096, smem);
        } else {
            float* hn = dechH + (size_t)t * 32768;
            dec_lstm_task(taskA * 2, t, tid, w, lane, hc, cp, hn, cA,
                          Whh4, Wh4, Wc4, g0, bprime, smem);
            if (taskB >= 0)
                dec_lstm_task(taskB * 2, t, tid, w, lane, hc, cp, hn, cB,
                              Whh4, Wh4, Wc4, g0, bprime, smem);
        }
        bar_arrive(flags, bi, (unsigned)(t + 1));
    }
}

// ---- post-pass: dout[b][tau] = Wo[255].[h^{(tau+1)}; ctx_tau] + bo[255] --
__global__ __launch_bounds__(256) void k_dout(
    const float* __restrict__ dechH, const float* __restrict__ ctxH,
    const float* __restrict__ Wo, const float* __restrict__ bo,
    float* __restrict__ dout)
{
    __shared__ float part[256];
    int tau = blockIdx.x;            // 0..95
    int tid = threadIdx.x;
    int lane = tid & 63;             // = b
    int w = tid >> 6;                // 0..3, each wave does 144 of 576
    const float* hq = dechH + (size_t)tau * 32768;
    const float* cq = ctxH + (size_t)tau * 4096;
    const float* wrow = Wo + 255 * 576;
    float acc = 0.f;
    for (int i = w * 144; i < w * 144 + 144; ++i) {
        float cat;
        if (i < 512) cat = hq[(i >> 2) * 256 + lane * 4 + (i & 3)];
        else         cat = cq[((i - 512) >> 2) * 256 + lane * 4 + ((i - 512) & 3)];
        acc = fmaf(wrow[i], cat, acc);
    }
    part[w * 64 + lane] = acc;
    __syncthreads();
    if (tid < 64) {
        float s = bo[255];
        #pragma unroll
        for (int ww = 0; ww < 4; ++ww) s += part[ww * 64 + tid];
        dout[tid * 96 + tau] = s;
    }
}

} // namespace

extern "C" void kernel_launch(void* const* d_in, const int* in_sizes, int n_in,
                              void* d_out, int out_size, void* d_ws, size_t ws_size,
                              hipStream_t stream)
{
    (void)in_sizes; (void)n_in; (void)out_size; (void)ws_size;
    const float* input_seq = (const float*)d_in[0];
    const float* h0     = (const float*)d_in[1];
    const float* c0     = (const float*)d_in[2];
    const float* W_ih_e = (const float*)d_in[3];
    const float* W_hh_e = (const float*)d_in[4];
    const float* b_e    = (const float*)d_in[5];
    const float* W_ih_d = (const float*)d_in[6];
    const float* W_hh_d = (const float*)d_in[7];
    const float* b_d    = (const float*)d_in[8];
    const float* We_p   = (const float*)d_in[9];
    const float* be_p   = (const float*)d_in[10];
    const float* Wh_p   = (const float*)d_in[11];
    const float* bh_p   = (const float*)d_in[12];
    const float* Wa     = (const float*)d_in[13];
    const float* ba     = (const float*)d_in[14];
    const float* v      = (const float*)d_in[15];
    const float* Wo     = (const float*)d_in[16];
    const float* bo     = (const float*)d_in[17];
    float* out = (float*)d_out;

    unsigned* encFlags = (unsigned*)d_ws;       // 256 words
    unsigned* decFlags = encFlags + 256;        // 256 words
    float* ws       = (float*)d_ws + 1024;      // 4KB offset
    float* xT       = ws;                       // 8388608 (dead after enc/g0)
    float* encH     = xT + 8388608;             // 513*32768 = 16809984
    float* cT       = encH + 16809984;          // 32768
    float* We_pT    = cT + 32768;               // 32768
    float* Wh_pT    = We_pT + 32768;            // 32768
    float* WahT     = Wh_pT + 32768;            // 4096
    float* WaeT     = WahT + 4096;              // 4096
    float* encProj  = WaeT + 4096;              // 2097152
    float* attnPre  = encProj + 2097152;        // 2097152
    float* dechH    = attnPre + 2097152;        // 96*32768 = 3145728
    float* ctxH     = dechH + 3145728;          // 96*4096 = 393216
    float* Wh       = ctxH + 393216;            // 2048*512 = 1048576
    float* Wc       = Wh + 1048576;             // 2048*64 = 131072
    float* bprime   = Wc + 131072;              // 2048
    float* g0       = bprime + 2048;            // 2048*64 = 131072
    float* attnPreT = xT;                       // aliases dead xT region (2M)

    hipMemsetAsync(d_ws, 0, 4096, stream);      // zero barrier flags
    k_transpose_input<<<2048, 256, 0, stream>>>(input_seq, (float4*)xT);
    k_prep<<<544, 256, 0, stream>>>(We_p, Wh_p, h0, c0, Wa,
                                    We_pT, Wh_pT, encH, cT, WahT, WaeT);
    k_prep_wcomb<<<2048, 256, 0, stream>>>(W_ih_d, W_hh_d, Wo, b_d, bo,
                                           Wh, Wc, bprime);
    k_prep_g0<<<512, 256, 0, stream>>>((const float4*)(xT + (size_t)511 * 16384),
                                       W_ih_d, b_d, g0);
    k_enc_persistent<<<256, 512, 0, stream>>>((const float4*)xT, encH, cT,
                                              W_ih_e, W_hh_e, b_e, encFlags);
    k_proj_attn<<<1024, 256, 0, stream>>>(encH, We_pT, be_p, WaeT, ba,
                                          encProj, attnPre);
    k_attn_transpose<<<512, 256, 0, stream>>>(attnPre, attnPreT);
    k_dec_persistent<<<256, 512, 0, stream>>>(encH + (size_t)512 * 32768,
                                              dechH, cT,
                                              W_hh_d, Wh, Wc, g0, bprime,
                                              Wh_pT, bh_p, WahT, v,
                                              attnPreT, encProj, ctxH,
                                              decFlags);
    k_dout<<<96, 256, 0, stream>>>(dechH, ctxH, Wo, bo, out);
}